// Round 1
// baseline (980.074 us; speedup 1.0000x reference)
//
#include <hip/hip_runtime.h>

// GCN forward + NCut loss on MI355X.
// Pipeline: CSR build (hist/scan/scatter) -> GEMM1 (fp32 tiled) ->
// SPMM1+bias+relu+fused GEMM2 -> SPMM2+head+softmax+Gamma -> edge loss -> finalize.
// loss = 16 - sum_e w_e * sum_j Y[row,j]*Y[col,j]/Gamma[j]   (first term telescopes to G=16)

constexpr int NN = 50000;
constexpr int NE = 1600000;
constexpr int F0 = 512;
constexpr int F1 = 256;
constexpr int G  = 16;

// ---------------- CSR build ----------------
__global__ __launch_bounds__(256) void k_hist(const int* __restrict__ row, int* __restrict__ counts) {
    int e = blockIdx.x * 256 + threadIdx.x;
    if (e < NE) atomicAdd(&counts[row[e]], 1);
}

__global__ __launch_bounds__(1024) void k_scan(const int* __restrict__ counts, int* __restrict__ rowptr,
                                               int* __restrict__ cursor) {
    __shared__ int sh[1024];
    const int tid = threadIdx.x;
    const int CH = (NN + 1023) / 1024;   // 49
    int start = tid * CH;
    int end = start + CH; if (end > NN) end = NN;
    int sum = 0;
    for (int i = start; i < end; ++i) sum += counts[i];
    sh[tid] = sum;
    __syncthreads();
    for (int off = 1; off < 1024; off <<= 1) {
        int v = (tid >= off) ? sh[tid - off] : 0;
        __syncthreads();
        sh[tid] += v;
        __syncthreads();
    }
    int running = sh[tid] - sum;   // exclusive prefix
    for (int i = start; i < end; ++i) {
        rowptr[i] = running;
        cursor[i] = running;
        running += counts[i];
    }
    if (tid == 1023) rowptr[NN] = sh[1023];
}

__global__ __launch_bounds__(256) void k_scatter(const int* __restrict__ row, const int* __restrict__ col,
                                                 const float* __restrict__ ev, int* __restrict__ cursor,
                                                 int* __restrict__ colS, float* __restrict__ wS) {
    int e = blockIdx.x * 256 + threadIdx.x;
    if (e < NE) {
        int r = row[e];
        int p = atomicAdd(&cursor[r], 1);
        colS[p] = col[e];
        wS[p]   = ev[e];
    }
}

// ---------------- GEMM1: XW = H @ W1  (50000x512 @ 512x256, fp32) ----------------
// 128x128 tile, BK=8, 256 threads, 8x8 microtile.
__global__ __launch_bounds__(256) void k_gemm1(const float* __restrict__ H, const float* __restrict__ W1,
                                               float* __restrict__ XW) {
    __shared__ float As[8][132];
    __shared__ float Bs[8][132];
    const int tid = threadIdx.x;
    const int bm = blockIdx.x * 128;
    const int bn = blockIdx.y * 128;
    const int ty = tid >> 4, tx = tid & 15;
    const int lrA = tid >> 1;           // 0..127
    const int lkA = (tid & 1) << 2;     // 0 or 4
    const int lkB = tid >> 5;           // 0..7
    const int lnB = (tid & 31) << 2;    // 0..124
    const int gRow = bm + lrA;

    float acc[8][8];
#pragma unroll
    for (int i = 0; i < 8; ++i)
#pragma unroll
        for (int j = 0; j < 8; ++j) acc[i][j] = 0.f;

    float4 a4 = make_float4(0.f, 0.f, 0.f, 0.f);
    if (gRow < NN) a4 = *(const float4*)&H[gRow * F0 + lkA];
    float4 b4 = *(const float4*)&W1[lkB * F1 + bn + lnB];

    for (int k0 = 0; k0 < F0; k0 += 8) {
        __syncthreads();
        As[lkA + 0][lrA] = a4.x;
        As[lkA + 1][lrA] = a4.y;
        As[lkA + 2][lrA] = a4.z;
        As[lkA + 3][lrA] = a4.w;
        *(float4*)&Bs[lkB][lnB] = b4;
        __syncthreads();
        if (k0 + 8 < F0) {     // prefetch next tile (overlaps compute below)
            a4 = make_float4(0.f, 0.f, 0.f, 0.f);
            if (gRow < NN) a4 = *(const float4*)&H[gRow * F0 + k0 + 8 + lkA];
            b4 = *(const float4*)&W1[(k0 + 8 + lkB) * F1 + bn + lnB];
        }
#pragma unroll
        for (int k = 0; k < 8; ++k) {
            float a[8], b[8];
            *(float4*)&a[0] = *(const float4*)&As[k][ty * 8];
            *(float4*)&a[4] = *(const float4*)&As[k][ty * 8 + 4];
            *(float4*)&b[0] = *(const float4*)&Bs[k][tx * 8];
            *(float4*)&b[4] = *(const float4*)&Bs[k][tx * 8 + 4];
#pragma unroll
            for (int i = 0; i < 8; ++i)
#pragma unroll
                for (int j = 0; j < 8; ++j)
                    acc[i][j] = fmaf(a[i], b[j], acc[i][j]);
        }
    }
#pragma unroll
    for (int i = 0; i < 8; ++i) {
        int r = bm + ty * 8 + i;
        if (r < NN) {
            float4 o0 = make_float4(acc[i][0], acc[i][1], acc[i][2], acc[i][3]);
            float4 o1 = make_float4(acc[i][4], acc[i][5], acc[i][6], acc[i][7]);
            *(float4*)&XW[r * F1 + bn + tx * 8]     = o0;
            *(float4*)&XW[r * F1 + bn + tx * 8 + 4] = o1;
        }
    }
}

// ---------------- SPMM1 + bias + relu + fused GEMM2 ----------------
// wave per node: acc4 = sum_e w * XW[col]; D[n]=sum w; h=relu(acc+b1);
// Z[n][j] = sum_k h[k]*W2[k][j]  via per-lane partials + 64-lane butterfly.
__global__ __launch_bounds__(256) void k_spmm1(const float* __restrict__ XW, const int* __restrict__ rowptr,
                                               const int* __restrict__ colS, const float* __restrict__ wS,
                                               const float* __restrict__ b1, const float* __restrict__ W2,
                                               float* __restrict__ Z, float* __restrict__ Dv) {
    __shared__ float W2T[G * F1];   // W2T[j][k] = W2[k][j], 16KB
    const int tid = threadIdx.x;
    for (int idx = tid; idx < F1 * G; idx += 256) {
        int k = idx >> 4, j = idx & 15;
        W2T[j * F1 + k] = W2[idx];
    }
    __syncthreads();
    const int lane = tid & 63;
    const int n = blockIdx.x * 4 + (tid >> 6);
    if (n >= NN) return;
    const int s = rowptr[n], e = rowptr[n + 1];
    const float4* XW4 = (const float4*)XW;

    float4 acc = make_float4(0.f, 0.f, 0.f, 0.f);
    float wsum = 0.f;
    int i = s;
    for (; i + 2 <= e; i += 2) {
        int c0 = colS[i], c1 = colS[i + 1];
        float w0 = wS[i], w1 = wS[i + 1];
        float4 g0 = XW4[c0 * 64 + lane];
        float4 g1 = XW4[c1 * 64 + lane];
        acc.x = fmaf(w0, g0.x, acc.x); acc.y = fmaf(w0, g0.y, acc.y);
        acc.z = fmaf(w0, g0.z, acc.z); acc.w = fmaf(w0, g0.w, acc.w);
        acc.x = fmaf(w1, g1.x, acc.x); acc.y = fmaf(w1, g1.y, acc.y);
        acc.z = fmaf(w1, g1.z, acc.z); acc.w = fmaf(w1, g1.w, acc.w);
        wsum += w0 + w1;
    }
    if (i < e) {
        int c = colS[i]; float w = wS[i];
        float4 g = XW4[c * 64 + lane];
        acc.x = fmaf(w, g.x, acc.x); acc.y = fmaf(w, g.y, acc.y);
        acc.z = fmaf(w, g.z, acc.z); acc.w = fmaf(w, g.w, acc.w);
        wsum += w;
    }
    if (lane == 0) Dv[n] = wsum;

    float4 bb = *(const float4*)&b1[lane * 4];
    float4 h;
    h.x = fmaxf(acc.x + bb.x, 0.f);
    h.y = fmaxf(acc.y + bb.y, 0.f);
    h.z = fmaxf(acc.z + bb.z, 0.f);
    h.w = fmaxf(acc.w + bb.w, 0.f);

    float p[G];
#pragma unroll
    for (int j = 0; j < G; ++j) {
        float4 w4 = *(const float4*)&W2T[j * F1 + lane * 4];
        p[j] = h.x * w4.x + h.y * w4.y + h.z * w4.z + h.w * w4.w;
    }
#pragma unroll
    for (int off = 1; off < 64; off <<= 1) {
#pragma unroll
        for (int j = 0; j < G; ++j) p[j] += __shfl_xor(p[j], off, 64);
    }
    if (lane == 0) {
        float* zp = &Z[n * G];
        *(float4*)&zp[0]  = make_float4(p[0], p[1], p[2], p[3]);
        *(float4*)&zp[4]  = make_float4(p[4], p[5], p[6], p[7]);
        *(float4*)&zp[8]  = make_float4(p[8], p[9], p[10], p[11]);
        *(float4*)&zp[12] = make_float4(p[12], p[13], p[14], p[15]);
    }
}

// ---------------- SPMM2 + bias + relu + head + softmax + Gamma ----------------
__global__ __launch_bounds__(256) void k_head(const float* __restrict__ Z, const int* __restrict__ rowptr,
                                              const int* __restrict__ colS, const float* __restrict__ wS,
                                              const float* __restrict__ b2, const float* __restrict__ Wl,
                                              const float* __restrict__ bl, const float* __restrict__ Dv,
                                              float* __restrict__ Y, float* __restrict__ Gamma) {
    __shared__ float WlS[G * G];
    __shared__ float gsh[G];
    const int tid = threadIdx.x;
    if (tid < G * G) WlS[tid] = Wl[tid];
    if (tid < G) gsh[tid] = 0.f;
    __syncthreads();
    const int lane = tid & 63;
    const int q = lane >> 4, j = lane & 15;
    const float b2j = b2[j], blj = bl[j];
    float gacc = 0.f;
    const int nwaves = gridDim.x * 4;
    for (int n = blockIdx.x * 4 + (tid >> 6); n < NN; n += nwaves) {
        const int s = rowptr[n], e = rowptr[n + 1];
        float acc = 0.f;
        for (int b = s + q; b < e; b += 4) {
            int c = colS[b];
            acc = fmaf(wS[b], Z[c * G + j], acc);
        }
        acc += __shfl_xor(acc, 16, 64);
        acc += __shfl_xor(acc, 32, 64);
        float h2 = fmaxf(acc + b2j, 0.f);
        float s3 = 0.f;
#pragma unroll
        for (int k = 0; k < G; ++k) s3 = fmaf(__shfl(h2, k, 64), WlS[k * G + j], s3);
        float h3 = fmaxf(s3 + blj, 0.f);
        float m = h3;
        m = fmaxf(m, __shfl_xor(m, 1, 64));
        m = fmaxf(m, __shfl_xor(m, 2, 64));
        m = fmaxf(m, __shfl_xor(m, 4, 64));
        m = fmaxf(m, __shfl_xor(m, 8, 64));
        float ex = __expf(h3 - m);
        float se = ex;
        se += __shfl_xor(se, 1, 64);
        se += __shfl_xor(se, 2, 64);
        se += __shfl_xor(se, 4, 64);
        se += __shfl_xor(se, 8, 64);
        float y = ex / se;
        if (lane < G) Y[n * G + j] = y;
        gacc = fmaf(y, Dv[n], gacc);   // identical across q groups; dedup below
    }
    if (lane < G) atomicAdd(&gsh[j], gacc);
    __syncthreads();
    if (tid < G) atomicAdd(&Gamma[tid], gsh[tid]);
}

// ---------------- edge loss: sum_e w_e * dot(Y[r]*invGamma, Y[c]) ----------------
__global__ __launch_bounds__(256) void k_loss(const int* __restrict__ row, const int* __restrict__ col,
                                              const float* __restrict__ ev, const float* __restrict__ Y,
                                              const float* __restrict__ Gamma, float* __restrict__ lossAcc) {
    __shared__ __align__(16) float ig[G];
    __shared__ float pw[4];
    const int tid = threadIdx.x;
    if (tid < G) ig[tid] = 1.0f / Gamma[tid];
    __syncthreads();
    float4 g0 = ((const float4*)ig)[0];
    float4 g1 = ((const float4*)ig)[1];
    float4 g2 = ((const float4*)ig)[2];
    float4 g3 = ((const float4*)ig)[3];
    float part = 0.f;
    for (int e = blockIdx.x * 256 + tid; e < NE; e += gridDim.x * 256) {
        int r = row[e], c = col[e];
        float w = ev[e];
        const float4* yr = (const float4*)(Y + r * G);
        const float4* yc = (const float4*)(Y + c * G);
        float4 a, b;
        float t = 0.f;
        a = yr[0]; b = yc[0];
        t += a.x * b.x * g0.x + a.y * b.y * g0.y + a.z * b.z * g0.z + a.w * b.w * g0.w;
        a = yr[1]; b = yc[1];
        t += a.x * b.x * g1.x + a.y * b.y * g1.y + a.z * b.z * g1.z + a.w * b.w * g1.w;
        a = yr[2]; b = yc[2];
        t += a.x * b.x * g2.x + a.y * b.y * g2.y + a.z * b.z * g2.z + a.w * b.w * g2.w;
        a = yr[3]; b = yc[3];
        t += a.x * b.x * g3.x + a.y * b.y * g3.y + a.z * b.z * g3.z + a.w * b.w * g3.w;
        part = fmaf(w, t, part);
    }
#pragma unroll
    for (int off = 1; off < 64; off <<= 1) part += __shfl_xor(part, off, 64);
    if ((tid & 63) == 0) pw[tid >> 6] = part;
    __syncthreads();
    if (tid == 0) atomicAdd(lossAcc, pw[0] + pw[1] + pw[2] + pw[3]);
}

__global__ void k_final(const float* __restrict__ lossAcc, float* __restrict__ out) {
    out[0] = 16.0f - lossAcc[0];
}

// ---------------- launcher ----------------
static inline size_t alignup(size_t x) { return (x + 255) & ~(size_t)255; }

extern "C" void kernel_launch(void* const* d_in, const int* in_sizes, int n_in,
                              void* d_out, int out_size, void* d_ws, size_t ws_size,
                              hipStream_t stream) {
    const float* H  = (const float*)d_in[0];
    const int*   ei = (const int*)d_in[1];
    const float* ev = (const float*)d_in[2];
    const float* W1 = (const float*)d_in[3];
    const float* b1 = (const float*)d_in[4];
    const float* W2 = (const float*)d_in[5];
    const float* b2 = (const float*)d_in[6];
    const float* Wl = (const float*)d_in[7];
    const float* bl = (const float*)d_in[8];
    const int* row = ei;
    const int* col = ei + NE;

    char* base = (char*)d_ws;
    size_t off = 0;
    float* XW     = (float*)(base + off); off = alignup(off + (size_t)NN * F1 * 4);
    float* Z      = (float*)(base + off); off = alignup(off + (size_t)NN * G * 4);
    float* Y      = (float*)(base + off); off = alignup(off + (size_t)NN * G * 4);
    float* Dv     = (float*)(base + off); off = alignup(off + (size_t)NN * 4);
    float* Gamma  = (float*)(base + off); off = alignup(off + (size_t)G * 4);
    float* lossA  = (float*)(base + off); off = alignup(off + 4);
    int*   counts = (int*)(base + off);   off = alignup(off + (size_t)NN * 4);
    int*   rowptr = (int*)(base + off);   off = alignup(off + (size_t)(NN + 1) * 4);
    int*   cursor = (int*)(base + off);   off = alignup(off + (size_t)NN * 4);
    int*   colS   = (int*)(base + off);   off = alignup(off + (size_t)NE * 4);
    float* wS     = (float*)(base + off); off = alignup(off + (size_t)NE * 4);
    // total ~71.2 MB

    hipMemsetAsync(counts, 0, (size_t)NN * 4, stream);
    hipMemsetAsync(Gamma, 0, G * 4, stream);
    hipMemsetAsync(lossA, 0, 4, stream);

    k_hist<<<dim3(NE / 256), dim3(256), 0, stream>>>(row, counts);
    k_scan<<<dim3(1), dim3(1024), 0, stream>>>(counts, rowptr, cursor);
    k_scatter<<<dim3(NE / 256), dim3(256), 0, stream>>>(row, col, ev, cursor, colS, wS);
    k_gemm1<<<dim3((NN + 127) / 128, F1 / 128), dim3(256), 0, stream>>>(H, W1, XW);
    k_spmm1<<<dim3((NN + 3) / 4), dim3(256), 0, stream>>>(XW, rowptr, colS, wS, b1, W2, Z, Dv);
    k_head<<<dim3(512), dim3(256), 0, stream>>>(Z, rowptr, colS, wS, b2, Wl, bl, Dv, Y, Gamma);
    k_loss<<<dim3(1024), dim3(256), 0, stream>>>(row, col, ev, Y, Gamma, lossA);
    k_final<<<dim3(1), dim3(1), 0, stream>>>(lossA, (float*)d_out);
}

// Round 2
// 813.384 us; speedup vs baseline: 1.2049x; 1.2049x over previous
//
#include <hip/hip_runtime.h>

// GCN forward + NCut loss on MI355X.
// R2: XW stored bf16 (halves spmm1 gather bytes, 2x L2 residency) +
//     GEMM1 rewritten as bf16 MFMA (16x16x32), fused f32->bf16 A-staging.
// loss = 16 - sum_e w_e * sum_j Y[row,j]*Y[col,j]/Gamma[j]

constexpr int NN = 50000;
constexpr int NE = 1600000;
constexpr int F0 = 512;
constexpr int F1 = 256;
constexpr int G  = 16;

typedef short  s16x8 __attribute__((ext_vector_type(8)));
typedef float  f32x4 __attribute__((ext_vector_type(4)));

static __device__ __forceinline__ unsigned short f2bf(float f) {
    union { float f; unsigned u; } v; v.f = f;
    unsigned r = (v.u + 0x7FFFu + ((v.u >> 16) & 1u)) >> 16;   // RNE
    return (unsigned short)r;
}
static __device__ __forceinline__ float bf2f(unsigned short u) {
    union { unsigned u; float f; } v; v.u = (unsigned)u << 16;
    return v.f;
}

// ---------------- CSR build ----------------
__global__ __launch_bounds__(256) void k_hist(const int* __restrict__ row, int* __restrict__ counts) {
    int e = blockIdx.x * 256 + threadIdx.x;
    if (e < NE) atomicAdd(&counts[row[e]], 1);
}

__global__ __launch_bounds__(1024) void k_scan(const int* __restrict__ counts, int* __restrict__ rowptr,
                                               int* __restrict__ cursor) {
    __shared__ int sh[1024];
    const int tid = threadIdx.x;
    const int CH = (NN + 1023) / 1024;
    int start = tid * CH;
    int end = start + CH; if (end > NN) end = NN;
    int sum = 0;
    for (int i = start; i < end; ++i) sum += counts[i];
    sh[tid] = sum;
    __syncthreads();
    for (int off = 1; off < 1024; off <<= 1) {
        int v = (tid >= off) ? sh[tid - off] : 0;
        __syncthreads();
        sh[tid] += v;
        __syncthreads();
    }
    int running = sh[tid] - sum;
    for (int i = start; i < end; ++i) {
        rowptr[i] = running;
        cursor[i] = running;
        running += counts[i];
    }
    if (tid == 1023) rowptr[NN] = sh[1023];
}

__global__ __launch_bounds__(256) void k_scatter(const int* __restrict__ row, const int* __restrict__ col,
                                                 const float* __restrict__ ev, int* __restrict__ cursor,
                                                 int* __restrict__ colS, float* __restrict__ wS) {
    int e = blockIdx.x * 256 + threadIdx.x;
    if (e < NE) {
        int r = row[e];
        int p = atomicAdd(&cursor[r], 1);
        colS[p] = col[e];
        wS[p]   = ev[e];
    }
}

// ---------------- W1 pre-cast+transpose: W1t[n][k] = bf16(W1[k][n]) ----------------
__global__ __launch_bounds__(256) void k_castW1(const float* __restrict__ W1, unsigned short* __restrict__ W1t) {
    int idx = blockIdx.x * 256 + threadIdx.x;       // idx over 512*256, coalesced read
    if (idx < F0 * F1) {
        int k = idx >> 8, n = idx & 255;
        W1t[n * F0 + k] = f2bf(W1[idx]);
    }
}

// ---------------- GEMM1 (bf16 MFMA): XW = bf16(H @ W1), [50000][256] bf16 ----------------
// 128x128 tile, BK=64, 256 threads = 4 waves (2x2 of 64x64), 16x16x32 MFMA.
__global__ __launch_bounds__(256) void k_gemm1(const float* __restrict__ H, const unsigned short* __restrict__ W1t,
                                               unsigned short* __restrict__ XW) {
    __shared__ unsigned short As[128][72];   // [m][k], +8 pad (2-way max conflict)
    __shared__ unsigned short Bs[128][72];   // [n][k]
    const int tid  = threadIdx.x;
    const int lane = tid & 63;
    const int wave = tid >> 6;
    const int bm = blockIdx.x * 128;
    const int bn = blockIdx.y * 128;
    const int m_off = (wave & 1) * 64;
    const int n_off = (wave >> 1) * 64;
    const int l15  = lane & 15;
    const int quad = lane >> 4;

    f32x4 acc[4][4];
#pragma unroll
    for (int i = 0; i < 4; ++i)
#pragma unroll
        for (int j = 0; j < 4; ++j) acc[i][j] = (f32x4)0.f;

    const int arow = tid >> 4;        // 0..15  (A staging: 16 rows/pass, 16 thr/row)
    const int akq  = tid & 15;        // float4 index within 64-k chunk
    const int brow = tid >> 3;        // 0..31  (B staging: 32 rows/pass, 8 thr/row)
    const int bkq  = tid & 7;         // ushort8 index within 64-k chunk

    for (int k0 = 0; k0 < F0; k0 += 64) {
        __syncthreads();
        // stage A: rows bm..bm+127, k0..k0+63, convert f32->bf16
#pragma unroll
        for (int p = 0; p < 8; ++p) {
            int r = p * 16 + arow;
            int gr = bm + r;
            float4 a4 = make_float4(0.f, 0.f, 0.f, 0.f);
            if (gr < NN) a4 = *(const float4*)&H[(size_t)gr * F0 + k0 + akq * 4];
            unsigned short* dst = &As[r][akq * 4];
            dst[0] = f2bf(a4.x); dst[1] = f2bf(a4.y); dst[2] = f2bf(a4.z); dst[3] = f2bf(a4.w);
        }
        // stage B: W1t rows bn..bn+127, k0..k0+63 (already bf16)
#pragma unroll
        for (int p = 0; p < 4; ++p) {
            int n = p * 32 + brow;
            uint4 b8 = *(const uint4*)&W1t[(bn + n) * F0 + k0 + bkq * 8];
            *(uint4*)&Bs[n][bkq * 8] = b8;
        }
        __syncthreads();
#pragma unroll
        for (int kk = 0; kk < 64; kk += 32) {
            s16x8 af[4], bfr[4];
#pragma unroll
            for (int mi = 0; mi < 4; ++mi)
                af[mi] = *(const s16x8*)&As[m_off + mi * 16 + l15][kk + quad * 8];
#pragma unroll
            for (int ni = 0; ni < 4; ++ni)
                bfr[ni] = *(const s16x8*)&Bs[n_off + ni * 16 + l15][kk + quad * 8];
#pragma unroll
            for (int mi = 0; mi < 4; ++mi)
#pragma unroll
                for (int ni = 0; ni < 4; ++ni)
                    acc[mi][ni] = __builtin_amdgcn_mfma_f32_16x16x32_bf16(af[mi], bfr[ni], acc[mi][ni], 0, 0, 0);
        }
    }
    // store: D row = quad*4+reg, col = l15  (verified C/D layout)
#pragma unroll
    for (int mi = 0; mi < 4; ++mi) {
        int r0 = bm + m_off + mi * 16 + quad * 4;
#pragma unroll
        for (int reg = 0; reg < 4; ++reg) {
            int gr = r0 + reg;
            if (gr < NN) {
                unsigned short* orow = &XW[(size_t)gr * F1 + bn + n_off];
#pragma unroll
                for (int ni = 0; ni < 4; ++ni)
                    orow[ni * 16 + l15] = f2bf(acc[mi][ni][reg]);
            }
        }
    }
}

// ---------------- SPMM1 + bias + relu + fused GEMM2 (bf16 gather) ----------------
__global__ __launch_bounds__(256) void k_spmm1(const unsigned short* __restrict__ XW, const int* __restrict__ rowptr,
                                               const int* __restrict__ colS, const float* __restrict__ wS,
                                               const float* __restrict__ b1, const float* __restrict__ W2,
                                               float* __restrict__ Z, float* __restrict__ Dv) {
    __shared__ float W2T[G * F1];   // W2T[j][k] = W2[k][j]
    const int tid = threadIdx.x;
    for (int idx = tid; idx < F1 * G; idx += 256) {
        int k = idx >> 4, j = idx & 15;
        W2T[j * F1 + k] = W2[idx];
    }
    __syncthreads();
    const int lane = tid & 63;
    const int n = blockIdx.x * 4 + (tid >> 6);
    if (n >= NN) return;
    const int s = rowptr[n], e = rowptr[n + 1];
    const ushort4* XW4 = (const ushort4*)XW;   // 8B per lane, row = 64 ushort4

    float4 acc = make_float4(0.f, 0.f, 0.f, 0.f);
    float wsum = 0.f;
    int i = s;
    for (; i + 2 <= e; i += 2) {
        int c0 = colS[i], c1 = colS[i + 1];
        float w0 = wS[i], w1 = wS[i + 1];
        ushort4 g0 = XW4[(size_t)c0 * 64 + lane];
        ushort4 g1 = XW4[(size_t)c1 * 64 + lane];
        acc.x = fmaf(w0, bf2f(g0.x), acc.x); acc.y = fmaf(w0, bf2f(g0.y), acc.y);
        acc.z = fmaf(w0, bf2f(g0.z), acc.z); acc.w = fmaf(w0, bf2f(g0.w), acc.w);
        acc.x = fmaf(w1, bf2f(g1.x), acc.x); acc.y = fmaf(w1, bf2f(g1.y), acc.y);
        acc.z = fmaf(w1, bf2f(g1.z), acc.z); acc.w = fmaf(w1, bf2f(g1.w), acc.w);
        wsum += w0 + w1;
    }
    if (i < e) {
        int c = colS[i]; float w = wS[i];
        ushort4 g = XW4[(size_t)c * 64 + lane];
        acc.x = fmaf(w, bf2f(g.x), acc.x); acc.y = fmaf(w, bf2f(g.y), acc.y);
        acc.z = fmaf(w, bf2f(g.z), acc.z); acc.w = fmaf(w, bf2f(g.w), acc.w);
        wsum += w;
    }
    if (lane == 0) Dv[n] = wsum;

    float4 bb = *(const float4*)&b1[lane * 4];
    float4 h;
    h.x = fmaxf(acc.x + bb.x, 0.f);
    h.y = fmaxf(acc.y + bb.y, 0.f);
    h.z = fmaxf(acc.z + bb.z, 0.f);
    h.w = fmaxf(acc.w + bb.w, 0.f);

    float p[G];
#pragma unroll
    for (int j = 0; j < G; ++j) {
        float4 w4 = *(const float4*)&W2T[j * F1 + lane * 4];
        p[j] = h.x * w4.x + h.y * w4.y + h.z * w4.z + h.w * w4.w;
    }
#pragma unroll
    for (int off = 1; off < 64; off <<= 1) {
#pragma unroll
        for (int j = 0; j < G; ++j) p[j] += __shfl_xor(p[j], off, 64);
    }
    if (lane == 0) {
        float* zp = &Z[n * G];
        *(float4*)&zp[0]  = make_float4(p[0], p[1], p[2], p[3]);
        *(float4*)&zp[4]  = make_float4(p[4], p[5], p[6], p[7]);
        *(float4*)&zp[8]  = make_float4(p[8], p[9], p[10], p[11]);
        *(float4*)&zp[12] = make_float4(p[12], p[13], p[14], p[15]);
    }
}

// ---------------- SPMM2 + bias + relu + head + softmax + Gamma ----------------
__global__ __launch_bounds__(256) void k_head(const float* __restrict__ Z, const int* __restrict__ rowptr,
                                              const int* __restrict__ colS, const float* __restrict__ wS,
                                              const float* __restrict__ b2, const float* __restrict__ Wl,
                                              const float* __restrict__ bl, const float* __restrict__ Dv,
                                              float* __restrict__ Y, float* __restrict__ Gamma) {
    __shared__ float WlS[G * G];
    __shared__ float gsh[G];
    const int tid = threadIdx.x;
    if (tid < G * G) WlS[tid] = Wl[tid];
    if (tid < G) gsh[tid] = 0.f;
    __syncthreads();
    const int lane = tid & 63;
    const int q = lane >> 4, j = lane & 15;
    const float b2j = b2[j], blj = bl[j];
    float gacc = 0.f;
    const int nwaves = gridDim.x * 4;
    for (int n = blockIdx.x * 4 + (tid >> 6); n < NN; n += nwaves) {
        const int s = rowptr[n], e = rowptr[n + 1];
        float acc = 0.f;
        for (int b = s + q; b < e; b += 4) {
            int c = colS[b];
            acc = fmaf(wS[b], Z[c * G + j], acc);
        }
        acc += __shfl_xor(acc, 16, 64);
        acc += __shfl_xor(acc, 32, 64);
        float h2 = fmaxf(acc + b2j, 0.f);
        float s3 = 0.f;
#pragma unroll
        for (int k = 0; k < G; ++k) s3 = fmaf(__shfl(h2, k, 64), WlS[k * G + j], s3);
        float h3 = fmaxf(s3 + blj, 0.f);
        float m = h3;
        m = fmaxf(m, __shfl_xor(m, 1, 64));
        m = fmaxf(m, __shfl_xor(m, 2, 64));
        m = fmaxf(m, __shfl_xor(m, 4, 64));
        m = fmaxf(m, __shfl_xor(m, 8, 64));
        float ex = __expf(h3 - m);
        float se = ex;
        se += __shfl_xor(se, 1, 64);
        se += __shfl_xor(se, 2, 64);
        se += __shfl_xor(se, 4, 64);
        se += __shfl_xor(se, 8, 64);
        float y = ex / se;
        if (lane < G) Y[n * G + j] = y;
        gacc = fmaf(y, Dv[n], gacc);
    }
    if (lane < G) atomicAdd(&gsh[j], gacc);
    __syncthreads();
    if (tid < G) atomicAdd(&Gamma[tid], gsh[tid]);
}

// ---------------- edge loss ----------------
__global__ __launch_bounds__(256) void k_loss(const int* __restrict__ row, const int* __restrict__ col,
                                              const float* __restrict__ ev, const float* __restrict__ Y,
                                              const float* __restrict__ Gamma, float* __restrict__ lossAcc) {
    __shared__ __align__(16) float ig[G];
    __shared__ float pw[4];
    const int tid = threadIdx.x;
    if (tid < G) ig[tid] = 1.0f / Gamma[tid];
    __syncthreads();
    float4 g0 = ((const float4*)ig)[0];
    float4 g1 = ((const float4*)ig)[1];
    float4 g2 = ((const float4*)ig)[2];
    float4 g3 = ((const float4*)ig)[3];
    float part = 0.f;
    for (int e = blockIdx.x * 256 + tid; e < NE; e += gridDim.x * 256) {
        int r = row[e], c = col[e];
        float w = ev[e];
        const float4* yr = (const float4*)(Y + r * G);
        const float4* yc = (const float4*)(Y + c * G);
        float4 a, b;
        float t = 0.f;
        a = yr[0]; b = yc[0];
        t += a.x * b.x * g0.x + a.y * b.y * g0.y + a.z * b.z * g0.z + a.w * b.w * g0.w;
        a = yr[1]; b = yc[1];
        t += a.x * b.x * g1.x + a.y * b.y * g1.y + a.z * b.z * g1.z + a.w * b.w * g1.w;
        a = yr[2]; b = yc[2];
        t += a.x * b.x * g2.x + a.y * b.y * g2.y + a.z * b.z * g2.z + a.w * b.w * g2.w;
        a = yr[3]; b = yc[3];
        t += a.x * b.x * g3.x + a.y * b.y * g3.y + a.z * b.z * g3.z + a.w * b.w * g3.w;
        part = fmaf(w, t, part);
    }
#pragma unroll
    for (int off = 1; off < 64; off <<= 1) part += __shfl_xor(part, off, 64);
    if ((tid & 63) == 0) pw[tid >> 6] = part;
    __syncthreads();
    if (tid == 0) atomicAdd(lossAcc, pw[0] + pw[1] + pw[2] + pw[3]);
}

__global__ void k_final(const float* __restrict__ lossAcc, float* __restrict__ out) {
    out[0] = 16.0f - lossAcc[0];
}

// ---------------- launcher ----------------
static inline size_t alignup(size_t x) { return (x + 255) & ~(size_t)255; }

extern "C" void kernel_launch(void* const* d_in, const int* in_sizes, int n_in,
                              void* d_out, int out_size, void* d_ws, size_t ws_size,
                              hipStream_t stream) {
    const float* H  = (const float*)d_in[0];
    const int*   ei = (const int*)d_in[1];
    const float* ev = (const float*)d_in[2];
    const float* W1 = (const float*)d_in[3];
    const float* b1 = (const float*)d_in[4];
    const float* W2 = (const float*)d_in[5];
    const float* b2 = (const float*)d_in[6];
    const float* Wl = (const float*)d_in[7];
    const float* bl = (const float*)d_in[8];
    const int* row = ei;
    const int* col = ei + NE;

    char* base = (char*)d_ws;
    size_t off = 0;
    unsigned short* XW  = (unsigned short*)(base + off); off = alignup(off + (size_t)NN * F1 * 2);
    unsigned short* W1t = (unsigned short*)(base + off); off = alignup(off + (size_t)F0 * F1 * 2);
    float* Z      = (float*)(base + off); off = alignup(off + (size_t)NN * G * 4);
    float* Y      = (float*)(base + off); off = alignup(off + (size_t)NN * G * 4);
    float* Dv     = (float*)(base + off); off = alignup(off + (size_t)NN * 4);
    float* Gamma  = (float*)(base + off); off = alignup(off + (size_t)G * 4);
    float* lossA  = (float*)(base + off); off = alignup(off + 4);
    int*   counts = (int*)(base + off);   off = alignup(off + (size_t)NN * 4);
    int*   rowptr = (int*)(base + off);   off = alignup(off + (size_t)(NN + 1) * 4);
    int*   cursor = (int*)(base + off);   off = alignup(off + (size_t)NN * 4);
    int*   colS   = (int*)(base + off);   off = alignup(off + (size_t)NE * 4);
    float* wS     = (float*)(base + off); off = alignup(off + (size_t)NE * 4);

    hipMemsetAsync(counts, 0, (size_t)NN * 4, stream);
    hipMemsetAsync(Gamma, 0, G * 4, stream);
    hipMemsetAsync(lossA, 0, 4, stream);

    k_hist<<<dim3(NE / 256), dim3(256), 0, stream>>>(row, counts);
    k_scan<<<dim3(1), dim3(1024), 0, stream>>>(counts, rowptr, cursor);
    k_scatter<<<dim3(NE / 256), dim3(256), 0, stream>>>(row, col, ev, cursor, colS, wS);
    k_castW1<<<dim3((F0 * F1 + 255) / 256), dim3(256), 0, stream>>>(W1, W1t);
    k_gemm1<<<dim3((NN + 127) / 128, F1 / 128), dim3(256), 0, stream>>>(H, W1t, XW);
    k_spmm1<<<dim3((NN + 3) / 4), dim3(256), 0, stream>>>(XW, rowptr, colS, wS, b1, W2, Z, Dv);
    k_head<<<dim3(512), dim3(256), 0, stream>>>(Z, rowptr, colS, wS, b2, Wl, bl, Dv, Y, Gamma);
    k_loss<<<dim3(1024), dim3(256), 0, stream>>>(row, col, ev, Y, Gamma, lossA);
    k_final<<<dim3(1), dim3(1), 0, stream>>>(lossA, (float*)d_out);
}

// Round 3
// 704.693 us; speedup vs baseline: 1.3908x; 1.1542x over previous
//
#include <hip/hip_runtime.h>

// GCN forward + NCut loss on MI355X.
// R3: XW stored fp8-e4m3 (halves gather again, 12.8MB L2-resident), spmm1 MLP=4,
//     k_head 1 node/wave (12500 blocks) with bf16 Z, Gamma partial slots,
//     unrolled loss, int4 hist/scatter.
// loss = 16 - sum_e w_e * sum_j Y[row,j]*Y[col,j]/Gamma[j]

constexpr int NN = 50000;
constexpr int NE = 1600000;
constexpr int F0 = 512;
constexpr int F1 = 256;
constexpr int G  = 16;

typedef short  s16x8 __attribute__((ext_vector_type(8)));
typedef float  f32x4 __attribute__((ext_vector_type(4)));
typedef float  f32x2 __attribute__((ext_vector_type(2)));

static __device__ __forceinline__ unsigned short f2bf(float f) {
    union { float f; unsigned u; } v; v.f = f;
    unsigned r = (v.u + 0x7FFFu + ((v.u >> 16) & 1u)) >> 16;   // RNE
    return (unsigned short)r;
}
static __device__ __forceinline__ float bf2f(unsigned short u) {
    union { unsigned u; float f; } v; v.u = (unsigned)u << 16;
    return v.f;
}

// ---------------- CSR build ----------------
__global__ __launch_bounds__(256) void k_hist(const int* __restrict__ row, int* __restrict__ counts) {
    int idx = blockIdx.x * 256 + threadIdx.x;
    if (idx < NE / 4) {
        int4 r = ((const int4*)row)[idx];
        atomicAdd(&counts[r.x], 1);
        atomicAdd(&counts[r.y], 1);
        atomicAdd(&counts[r.z], 1);
        atomicAdd(&counts[r.w], 1);
    }
}

__global__ __launch_bounds__(1024) void k_scan(const int* __restrict__ counts, int* __restrict__ rowptr,
                                               int* __restrict__ cursor) {
    __shared__ int sh[1024];
    const int tid = threadIdx.x;
    const int CH = (NN + 1023) / 1024;
    int start = tid * CH;
    int end = start + CH; if (end > NN) end = NN;
    int sum = 0;
    for (int i = start; i < end; ++i) sum += counts[i];
    sh[tid] = sum;
    __syncthreads();
    for (int off = 1; off < 1024; off <<= 1) {
        int v = (tid >= off) ? sh[tid - off] : 0;
        __syncthreads();
        sh[tid] += v;
        __syncthreads();
    }
    int running = sh[tid] - sum;
    for (int i = start; i < end; ++i) {
        rowptr[i] = running;
        cursor[i] = running;
        running += counts[i];
    }
    if (tid == 1023) rowptr[NN] = sh[1023];
}

__global__ __launch_bounds__(256) void k_scatter(const int* __restrict__ row, const int* __restrict__ col,
                                                 const float* __restrict__ ev, int* __restrict__ cursor,
                                                 int* __restrict__ colS, float* __restrict__ wS) {
    int idx = blockIdx.x * 256 + threadIdx.x;
    if (idx < NE / 4) {
        int4   r = ((const int4*)row)[idx];
        int4   c = ((const int4*)col)[idx];
        float4 w = ((const float4*)ev)[idx];
        int p;
        p = atomicAdd(&cursor[r.x], 1); colS[p] = c.x; wS[p] = w.x;
        p = atomicAdd(&cursor[r.y], 1); colS[p] = c.y; wS[p] = w.y;
        p = atomicAdd(&cursor[r.z], 1); colS[p] = c.z; wS[p] = w.z;
        p = atomicAdd(&cursor[r.w], 1); colS[p] = c.w; wS[p] = w.w;
    }
}

// ---------------- W1 pre-cast+transpose: W1t[n][k] = bf16(W1[k][n]) ----------------
__global__ __launch_bounds__(256) void k_castW1(const float* __restrict__ W1, unsigned short* __restrict__ W1t) {
    int idx = blockIdx.x * 256 + threadIdx.x;
    if (idx < F0 * F1) {
        int k = idx >> 8, n = idx & 255;
        W1t[n * F0 + k] = f2bf(W1[idx]);
    }
}

// ---------------- GEMM1 (bf16 MFMA): XW = fp8(H @ W1), [50000][256] fp8-e4m3 ----------------
__global__ __launch_bounds__(256) void k_gemm1(const float* __restrict__ H, const unsigned short* __restrict__ W1t,
                                               unsigned char* __restrict__ XW) {
    __shared__ unsigned short As[128][72];
    __shared__ unsigned short Bs[128][72];
    const int tid  = threadIdx.x;
    const int lane = tid & 63;
    const int wave = tid >> 6;
    const int bm = blockIdx.x * 128;
    const int bn = blockIdx.y * 128;
    const int m_off = (wave & 1) * 64;
    const int n_off = (wave >> 1) * 64;
    const int l15  = lane & 15;
    const int quad = lane >> 4;

    f32x4 acc[4][4];
#pragma unroll
    for (int i = 0; i < 4; ++i)
#pragma unroll
        for (int j = 0; j < 4; ++j) acc[i][j] = (f32x4)0.f;

    const int arow = tid >> 4;
    const int akq  = tid & 15;
    const int brow = tid >> 3;
    const int bkq  = tid & 7;

    for (int k0 = 0; k0 < F0; k0 += 64) {
        __syncthreads();
#pragma unroll
        for (int p = 0; p < 8; ++p) {
            int r = p * 16 + arow;
            int gr = bm + r;
            float4 a4 = make_float4(0.f, 0.f, 0.f, 0.f);
            if (gr < NN) a4 = *(const float4*)&H[(size_t)gr * F0 + k0 + akq * 4];
            unsigned short* dst = &As[r][akq * 4];
            dst[0] = f2bf(a4.x); dst[1] = f2bf(a4.y); dst[2] = f2bf(a4.z); dst[3] = f2bf(a4.w);
        }
#pragma unroll
        for (int p = 0; p < 4; ++p) {
            int n = p * 32 + brow;
            uint4 b8 = *(const uint4*)&W1t[(bn + n) * F0 + k0 + bkq * 8];
            *(uint4*)&Bs[n][bkq * 8] = b8;
        }
        __syncthreads();
#pragma unroll
        for (int kk = 0; kk < 64; kk += 32) {
            s16x8 af[4], bfr[4];
#pragma unroll
            for (int mi = 0; mi < 4; ++mi)
                af[mi] = *(const s16x8*)&As[m_off + mi * 16 + l15][kk + quad * 8];
#pragma unroll
            for (int ni = 0; ni < 4; ++ni)
                bfr[ni] = *(const s16x8*)&Bs[n_off + ni * 16 + l15][kk + quad * 8];
#pragma unroll
            for (int mi = 0; mi < 4; ++mi)
#pragma unroll
                for (int ni = 0; ni < 4; ++ni)
                    acc[mi][ni] = __builtin_amdgcn_mfma_f32_16x16x32_bf16(af[mi], bfr[ni], acc[mi][ni], 0, 0, 0);
        }
    }
    // D row = quad*4+reg, col = l15; write fp8-e4m3 bytes
#pragma unroll
    for (int mi = 0; mi < 4; ++mi) {
        int r0 = bm + m_off + mi * 16 + quad * 4;
#pragma unroll
        for (int reg = 0; reg < 4; ++reg) {
            int gr = r0 + reg;
            if (gr < NN) {
                unsigned char* orow = &XW[(size_t)gr * F1 + bn + n_off];
#pragma unroll
                for (int ni = 0; ni < 4; ++ni) {
                    int pk = __builtin_amdgcn_cvt_pk_fp8_f32(acc[mi][ni][reg], 0.f, 0, false);
                    orow[ni * 16 + l15] = (unsigned char)(pk & 0xff);
                }
            }
        }
    }
}

// ---------------- SPMM1 + bias + relu + fused GEMM2 (fp8 gather, MLP=4) ----------------
__global__ __launch_bounds__(256) void k_spmm1(const unsigned char* __restrict__ XW, const int* __restrict__ rowptr,
                                               const int* __restrict__ colS, const float* __restrict__ wS,
                                               const float* __restrict__ b1, const float* __restrict__ W2,
                                               unsigned short* __restrict__ Z, float* __restrict__ Dv) {
    __shared__ float W2T[G * F1];
    const int tid = threadIdx.x;
    for (int idx = tid; idx < F1 * G; idx += 256) {
        int k = idx >> 4, j = idx & 15;
        W2T[j * F1 + k] = W2[idx];
    }
    __syncthreads();
    const int lane = tid & 63;
    const int n = blockIdx.x * 4 + (tid >> 6);   // NN = 12500*4 exactly
    const int s = __builtin_amdgcn_readfirstlane(rowptr[n]);
    const int e = __builtin_amdgcn_readfirstlane(rowptr[n + 1]);
    const unsigned* XWu = (const unsigned*)XW;   // row = 64 uints (4 fp8 each)

    float4 acc = make_float4(0.f, 0.f, 0.f, 0.f);
    float wsum = 0.f;
    int i = s;
    int pre = (s + 3) & ~3; if (pre > e) pre = e;
    for (; i < pre; ++i) {
        int c = colS[i]; float w = wS[i];
        unsigned g = XWu[(size_t)c * 64 + lane];
        f32x2 lo = __builtin_amdgcn_cvt_pk_f32_fp8(g, false);
        f32x2 hi = __builtin_amdgcn_cvt_pk_f32_fp8(g, true);
        acc.x = fmaf(w, lo.x, acc.x); acc.y = fmaf(w, lo.y, acc.y);
        acc.z = fmaf(w, hi.x, acc.z); acc.w = fmaf(w, hi.y, acc.w);
        wsum += w;
    }
    for (; i + 4 <= e; i += 4) {
        int4   c4 = *(const int4*)(colS + i);
        float4 w4 = *(const float4*)(wS + i);
        unsigned g0 = XWu[(size_t)c4.x * 64 + lane];
        unsigned g1 = XWu[(size_t)c4.y * 64 + lane];
        unsigned g2 = XWu[(size_t)c4.z * 64 + lane];
        unsigned g3 = XWu[(size_t)c4.w * 64 + lane];
        f32x2 v;
        v = __builtin_amdgcn_cvt_pk_f32_fp8(g0, false); acc.x = fmaf(w4.x, v.x, acc.x); acc.y = fmaf(w4.x, v.y, acc.y);
        v = __builtin_amdgcn_cvt_pk_f32_fp8(g0, true);  acc.z = fmaf(w4.x, v.x, acc.z); acc.w = fmaf(w4.x, v.y, acc.w);
        v = __builtin_amdgcn_cvt_pk_f32_fp8(g1, false); acc.x = fmaf(w4.y, v.x, acc.x); acc.y = fmaf(w4.y, v.y, acc.y);
        v = __builtin_amdgcn_cvt_pk_f32_fp8(g1, true);  acc.z = fmaf(w4.y, v.x, acc.z); acc.w = fmaf(w4.y, v.y, acc.w);
        v = __builtin_amdgcn_cvt_pk_f32_fp8(g2, false); acc.x = fmaf(w4.z, v.x, acc.x); acc.y = fmaf(w4.z, v.y, acc.y);
        v = __builtin_amdgcn_cvt_pk_f32_fp8(g2, true);  acc.z = fmaf(w4.z, v.x, acc.z); acc.w = fmaf(w4.z, v.y, acc.w);
        v = __builtin_amdgcn_cvt_pk_f32_fp8(g3, false); acc.x = fmaf(w4.w, v.x, acc.x); acc.y = fmaf(w4.w, v.y, acc.y);
        v = __builtin_amdgcn_cvt_pk_f32_fp8(g3, true);  acc.z = fmaf(w4.w, v.x, acc.z); acc.w = fmaf(w4.w, v.y, acc.w);
        wsum += w4.x + w4.y + w4.z + w4.w;
    }
    for (; i < e; ++i) {
        int c = colS[i]; float w = wS[i];
        unsigned g = XWu[(size_t)c * 64 + lane];
        f32x2 lo = __builtin_amdgcn_cvt_pk_f32_fp8(g, false);
        f32x2 hi = __builtin_amdgcn_cvt_pk_f32_fp8(g, true);
        acc.x = fmaf(w, lo.x, acc.x); acc.y = fmaf(w, lo.y, acc.y);
        acc.z = fmaf(w, hi.x, acc.z); acc.w = fmaf(w, hi.y, acc.w);
        wsum += w;
    }
    if (lane == 0) Dv[n] = wsum;

    float4 bb = *(const float4*)&b1[lane * 4];
    float4 h;
    h.x = fmaxf(acc.x + bb.x, 0.f);
    h.y = fmaxf(acc.y + bb.y, 0.f);
    h.z = fmaxf(acc.z + bb.z, 0.f);
    h.w = fmaxf(acc.w + bb.w, 0.f);

    float p[G];
#pragma unroll
    for (int j = 0; j < G; ++j) {
        float4 w4 = *(const float4*)&W2T[j * F1 + lane * 4];
        p[j] = h.x * w4.x + h.y * w4.y + h.z * w4.z + h.w * w4.w;
    }
#pragma unroll
    for (int off = 1; off < 64; off <<= 1) {
#pragma unroll
        for (int j = 0; j < G; ++j) p[j] += __shfl_xor(p[j], off, 64);
    }
    if (lane == 0) {
        unsigned zp[8];
#pragma unroll
        for (int j = 0; j < 8; ++j)
            zp[j] = (unsigned)f2bf(p[2 * j]) | ((unsigned)f2bf(p[2 * j + 1]) << 16);
        uint4* zo = (uint4*)&Z[n * G];
        zo[0] = make_uint4(zp[0], zp[1], zp[2], zp[3]);
        zo[1] = make_uint4(zp[4], zp[5], zp[6], zp[7]);
    }
}

// ---------------- SPMM2 + bias + relu + head + softmax + Gamma (1 node/wave) ----------------
__global__ __launch_bounds__(256) void k_head(const unsigned short* __restrict__ Zb, const int* __restrict__ rowptr,
                                              const int* __restrict__ colS, const float* __restrict__ wS,
                                              const float* __restrict__ b2, const float* __restrict__ Wl,
                                              const float* __restrict__ bl, const float* __restrict__ Dv,
                                              float* __restrict__ Y, float* __restrict__ GammaP) {
    __shared__ float WlS[G * G];
    __shared__ float gsh[G];
    const int tid = threadIdx.x;
    if (tid < G * G) WlS[tid] = Wl[tid];
    if (tid < G) gsh[tid] = 0.f;
    __syncthreads();
    const int lane = tid & 63;
    const int q = lane >> 4, j = lane & 15;
    const int n = blockIdx.x * 4 + (tid >> 6);   // NN = 12500*4 exactly
    const int s = __builtin_amdgcn_readfirstlane(rowptr[n]);
    const int e = __builtin_amdgcn_readfirstlane(rowptr[n + 1]);

    float a0 = 0.f, a1 = 0.f;
    int b = s + q;
    for (; b + 4 < e; b += 8) {
        int c0 = colS[b], c1 = colS[b + 4];
        float w0 = wS[b], w1 = wS[b + 4];
        a0 = fmaf(w0, bf2f(Zb[c0 * G + j]), a0);
        a1 = fmaf(w1, bf2f(Zb[c1 * G + j]), a1);
    }
    if (b < e) a0 = fmaf(wS[b], bf2f(Zb[colS[b] * G + j]), a0);
    float acc = a0 + a1;
    acc += __shfl_xor(acc, 16, 64);
    acc += __shfl_xor(acc, 32, 64);
    float h2 = fmaxf(acc + b2[j], 0.f);
    float s3 = 0.f;
#pragma unroll
    for (int k = 0; k < G; ++k) s3 = fmaf(__shfl(h2, k, 64), WlS[k * G + j], s3);
    float h3 = fmaxf(s3 + bl[j], 0.f);
    float m = h3;
    m = fmaxf(m, __shfl_xor(m, 1, 64));
    m = fmaxf(m, __shfl_xor(m, 2, 64));
    m = fmaxf(m, __shfl_xor(m, 4, 64));
    m = fmaxf(m, __shfl_xor(m, 8, 64));
    float ex = __expf(h3 - m);
    float se = ex;
    se += __shfl_xor(se, 1, 64);
    se += __shfl_xor(se, 2, 64);
    se += __shfl_xor(se, 4, 64);
    se += __shfl_xor(se, 8, 64);
    float y = ex / se;
    if (lane < G) {
        Y[n * G + j] = y;
        atomicAdd(&gsh[j], y * Dv[n]);
    }
    __syncthreads();
    if (tid < G) atomicAdd(&GammaP[(blockIdx.x & 63) * G + tid], gsh[tid]);
}

// ---------------- Gamma finalize: invG[j] = 1 / sum_b GammaP[b][j] ----------------
__global__ void k_gfin(const float* __restrict__ GammaP, float* __restrict__ invG) {
    int j = threadIdx.x;
    if (j < G) {
        float s = 0.f;
        for (int b = 0; b < 64; ++b) s += GammaP[b * G + j];
        invG[j] = 1.0f / s;
    }
}

// ---------------- edge loss ----------------
__global__ __launch_bounds__(256) void k_loss(const int* __restrict__ row, const int* __restrict__ col,
                                              const float* __restrict__ ev, const float* __restrict__ Y,
                                              const float* __restrict__ invG, float* __restrict__ lossAcc) {
    __shared__ __align__(16) float ig[G];
    __shared__ float pw[4];
    const int tid = threadIdx.x;
    if (tid < G) ig[tid] = invG[tid];
    __syncthreads();
    float4 g0 = ((const float4*)ig)[0];
    float4 g1 = ((const float4*)ig)[1];
    float4 g2 = ((const float4*)ig)[2];
    float4 g3 = ((const float4*)ig)[3];
    const int stride = gridDim.x * 256;
    float p0 = 0.f, p1 = 0.f;
    for (int e0 = blockIdx.x * 256 + tid; e0 < NE; e0 += 2 * stride) {
        {
            int r = row[e0], c = col[e0];
            float w = ev[e0];
            const float4* yr = (const float4*)(Y + r * G);
            const float4* yc = (const float4*)(Y + c * G);
            float4 a, b; float t = 0.f;
            a = yr[0]; b = yc[0];
            t += a.x * b.x * g0.x + a.y * b.y * g0.y + a.z * b.z * g0.z + a.w * b.w * g0.w;
            a = yr[1]; b = yc[1];
            t += a.x * b.x * g1.x + a.y * b.y * g1.y + a.z * b.z * g1.z + a.w * b.w * g1.w;
            a = yr[2]; b = yc[2];
            t += a.x * b.x * g2.x + a.y * b.y * g2.y + a.z * b.z * g2.z + a.w * b.w * g2.w;
            a = yr[3]; b = yc[3];
            t += a.x * b.x * g3.x + a.y * b.y * g3.y + a.z * b.z * g3.z + a.w * b.w * g3.w;
            p0 = fmaf(w, t, p0);
        }
        int e1 = e0 + stride;
        if (e1 < NE) {
            int r = row[e1], c = col[e1];
            float w = ev[e1];
            const float4* yr = (const float4*)(Y + r * G);
            const float4* yc = (const float4*)(Y + c * G);
            float4 a, b; float t = 0.f;
            a = yr[0]; b = yc[0];
            t += a.x * b.x * g0.x + a.y * b.y * g0.y + a.z * b.z * g0.z + a.w * b.w * g0.w;
            a = yr[1]; b = yc[1];
            t += a.x * b.x * g1.x + a.y * b.y * g1.y + a.z * b.z * g1.z + a.w * b.w * g1.w;
            a = yr[2]; b = yc[2];
            t += a.x * b.x * g2.x + a.y * b.y * g2.y + a.z * b.z * g2.z + a.w * b.w * g2.w;
            a = yr[3]; b = yc[3];
            t += a.x * b.x * g3.x + a.y * b.y * g3.y + a.z * b.z * g3.z + a.w * b.w * g3.w;
            p1 = fmaf(w, t, p1);
        }
    }
    float part = p0 + p1;
#pragma unroll
    for (int off = 1; off < 64; off <<= 1) part += __shfl_xor(part, off, 64);
    if ((tid & 63) == 0) pw[tid >> 6] = part;
    __syncthreads();
    if (tid == 0) atomicAdd(lossAcc, pw[0] + pw[1] + pw[2] + pw[3]);
}

__global__ void k_final(const float* __restrict__ lossAcc, float* __restrict__ out) {
    out[0] = 16.0f - lossAcc[0];
}

// ---------------- launcher ----------------
static inline size_t alignup(size_t x) { return (x + 255) & ~(size_t)255; }

extern "C" void kernel_launch(void* const* d_in, const int* in_sizes, int n_in,
                              void* d_out, int out_size, void* d_ws, size_t ws_size,
                              hipStream_t stream) {
    const float* H  = (const float*)d_in[0];
    const int*   ei = (const int*)d_in[1];
    const float* ev = (const float*)d_in[2];
    const float* W1 = (const float*)d_in[3];
    const float* b1 = (const float*)d_in[4];
    const float* W2 = (const float*)d_in[5];
    const float* b2 = (const float*)d_in[6];
    const float* Wl = (const float*)d_in[7];
    const float* bl = (const float*)d_in[8];
    const int* row = ei;
    const int* col = ei + NE;

    char* base = (char*)d_ws;
    size_t off = 0;
    unsigned char*  XW  = (unsigned char*)(base + off);  off = alignup(off + (size_t)NN * F1);
    unsigned short* W1t = (unsigned short*)(base + off); off = alignup(off + (size_t)F0 * F1 * 2);
    unsigned short* Z   = (unsigned short*)(base + off); off = alignup(off + (size_t)NN * G * 2);
    float* Y      = (float*)(base + off); off = alignup(off + (size_t)NN * G * 4);
    float* Dv     = (float*)(base + off); off = alignup(off + (size_t)NN * 4);
    float* GammaP = (float*)(base + off); off = alignup(off + (size_t)64 * G * 4);
    float* invG   = (float*)(base + off); off = alignup(off + (size_t)G * 4);
    float* lossA  = (float*)(base + off); off = alignup(off + 4);
    int*   counts = (int*)(base + off);   off = alignup(off + (size_t)NN * 4);
    int*   rowptr = (int*)(base + off);   off = alignup(off + (size_t)(NN + 1) * 4);
    int*   cursor = (int*)(base + off);   off = alignup(off + (size_t)NN * 4);
    int*   colS   = (int*)(base + off);   off = alignup(off + (size_t)NE * 4);
    float* wS     = (float*)(base + off); off = alignup(off + (size_t)NE * 4);

    hipMemsetAsync(counts, 0, (size_t)NN * 4, stream);
    hipMemsetAsync(GammaP, 0, (size_t)64 * G * 4, stream);
    hipMemsetAsync(lossA, 0, 4, stream);

    k_hist<<<dim3((NE / 4 + 255) / 256), dim3(256), 0, stream>>>(row, counts);
    k_scan<<<dim3(1), dim3(1024), 0, stream>>>(counts, rowptr, cursor);
    k_scatter<<<dim3((NE / 4 + 255) / 256), dim3(256), 0, stream>>>(row, col, ev, cursor, colS, wS);
    k_castW1<<<dim3((F0 * F1 + 255) / 256), dim3(256), 0, stream>>>(W1, W1t);
    k_gemm1<<<dim3((NN + 127) / 128, F1 / 128), dim3(256), 0, stream>>>(H, W1t, XW);
    k_spmm1<<<dim3(NN / 4), dim3(256), 0, stream>>>(XW, rowptr, colS, wS, b1, W2, Z, Dv);
    k_head<<<dim3(NN / 4), dim3(256), 0, stream>>>(Z, rowptr, colS, wS, b2, Wl, bl, Dv, Y, GammaP);
    k_gfin<<<dim3(1), dim3(64), 0, stream>>>(GammaP, invG);
    k_loss<<<dim3(1024), dim3(256), 0, stream>>>(row, col, ev, Y, invG, lossA);
    k_final<<<dim3(1), dim3(1), 0, stream>>>(lossA, (float*)d_out);
}

// Round 4
// 598.561 us; speedup vs baseline: 1.6374x; 1.1773x over previous
//
#include <hip/hip_runtime.h>

// GCN forward + NCut loss on MI355X.
// R4: spmm1 MLP=8; k_head 8-edges-per-load-instr layout (dword Z gathers, 16 in flight);
//     Y stored bf16 (halves loss traffic); parallel 3-kernel scan.
// loss = 16 - sum_e w_e * sum_j Y[row,j]*Y[col,j]/Gamma[j]

constexpr int NN = 50000;
constexpr int NE = 1600000;
constexpr int F0 = 512;
constexpr int F1 = 256;
constexpr int G  = 16;
constexpr int NB = (NN + 1023) / 1024;   // 49 scan blocks

typedef short  s16x8 __attribute__((ext_vector_type(8)));
typedef float  f32x4 __attribute__((ext_vector_type(4)));
typedef float  f32x2 __attribute__((ext_vector_type(2)));

static __device__ __forceinline__ unsigned short f2bf(float f) {
    union { float f; unsigned u; } v; v.f = f;
    unsigned r = (v.u + 0x7FFFu + ((v.u >> 16) & 1u)) >> 16;   // RNE
    return (unsigned short)r;
}
static __device__ __forceinline__ float bf2f(unsigned short u) {
    union { unsigned u; float f; } v; v.u = (unsigned)u << 16;
    return v.f;
}

// ---------------- CSR build ----------------
__global__ __launch_bounds__(256) void k_hist(const int* __restrict__ row, int* __restrict__ counts) {
    int idx = blockIdx.x * 256 + threadIdx.x;
    if (idx < NE / 4) {
        int4 r = ((const int4*)row)[idx];
        atomicAdd(&counts[r.x], 1);
        atomicAdd(&counts[r.y], 1);
        atomicAdd(&counts[r.z], 1);
        atomicAdd(&counts[r.w], 1);
    }
}

__global__ __launch_bounds__(1024) void k_scan1(const int* __restrict__ counts, int* __restrict__ bsum) {
    __shared__ int sh[1024];
    const int tid = threadIdx.x;
    int i = blockIdx.x * 1024 + tid;
    sh[tid] = (i < NN) ? counts[i] : 0;
    __syncthreads();
    for (int off = 512; off > 0; off >>= 1) {
        if (tid < off) sh[tid] += sh[tid + off];
        __syncthreads();
    }
    if (tid == 0) bsum[blockIdx.x] = sh[0];
}

__global__ void k_scan2(const int* __restrict__ bsum, int* __restrict__ bofs, int* __restrict__ rowptr) {
    const int tid = threadIdx.x;   // 64 threads
    int orig = (tid < NB) ? bsum[tid] : 0;
    int v = orig;
    for (int off = 1; off < 64; off <<= 1) {
        int t = __shfl_up(v, off, 64);
        if (tid >= off) v += t;
    }
    if (tid < NB) bofs[tid] = v - orig;   // exclusive
    if (tid == 63) rowptr[NN] = v;        // grand total
}

__global__ __launch_bounds__(1024) void k_scan3(const int* __restrict__ counts, const int* __restrict__ bofs,
                                                int* __restrict__ rowptr, int* __restrict__ cursor) {
    __shared__ int sh[1024];
    const int tid = threadIdx.x;
    int i = blockIdx.x * 1024 + tid;
    int orig = (i < NN) ? counts[i] : 0;
    sh[tid] = orig;
    __syncthreads();
    for (int off = 1; off < 1024; off <<= 1) {
        int t = (tid >= off) ? sh[tid - off] : 0;
        __syncthreads();
        sh[tid] += t;
        __syncthreads();
    }
    int ex = sh[tid] - orig + bofs[blockIdx.x];
    if (i < NN) { rowptr[i] = ex; cursor[i] = ex; }
}

__global__ __launch_bounds__(256) void k_scatter(const int* __restrict__ row, const int* __restrict__ col,
                                                 const float* __restrict__ ev, int* __restrict__ cursor,
                                                 int* __restrict__ colS, float* __restrict__ wS) {
    int idx = blockIdx.x * 256 + threadIdx.x;
    if (idx < NE / 4) {
        int4   r = ((const int4*)row)[idx];
        int4   c = ((const int4*)col)[idx];
        float4 w = ((const float4*)ev)[idx];
        int p;
        p = atomicAdd(&cursor[r.x], 1); colS[p] = c.x; wS[p] = w.x;
        p = atomicAdd(&cursor[r.y], 1); colS[p] = c.y; wS[p] = w.y;
        p = atomicAdd(&cursor[r.z], 1); colS[p] = c.z; wS[p] = w.z;
        p = atomicAdd(&cursor[r.w], 1); colS[p] = c.w; wS[p] = w.w;
    }
}

// ---------------- W1 pre-cast+transpose ----------------
__global__ __launch_bounds__(256) void k_castW1(const float* __restrict__ W1, unsigned short* __restrict__ W1t) {
    int idx = blockIdx.x * 256 + threadIdx.x;
    if (idx < F0 * F1) {
        int k = idx >> 8, n = idx & 255;
        W1t[n * F0 + k] = f2bf(W1[idx]);
    }
}

// ---------------- GEMM1 (bf16 MFMA): XW = fp8(H @ W1) ----------------
__global__ __launch_bounds__(256) void k_gemm1(const float* __restrict__ H, const unsigned short* __restrict__ W1t,
                                               unsigned char* __restrict__ XW) {
    __shared__ unsigned short As[128][72];
    __shared__ unsigned short Bs[128][72];
    const int tid  = threadIdx.x;
    const int lane = tid & 63;
    const int wave = tid >> 6;
    const int bm = blockIdx.x * 128;
    const int bn = blockIdx.y * 128;
    const int m_off = (wave & 1) * 64;
    const int n_off = (wave >> 1) * 64;
    const int l15  = lane & 15;
    const int quad = lane >> 4;

    f32x4 acc[4][4];
#pragma unroll
    for (int i = 0; i < 4; ++i)
#pragma unroll
        for (int j = 0; j < 4; ++j) acc[i][j] = (f32x4)0.f;

    const int arow = tid >> 4;
    const int akq  = tid & 15;
    const int brow = tid >> 3;
    const int bkq  = tid & 7;

    for (int k0 = 0; k0 < F0; k0 += 64) {
        __syncthreads();
#pragma unroll
        for (int p = 0; p < 8; ++p) {
            int r = p * 16 + arow;
            int gr = bm + r;
            float4 a4 = make_float4(0.f, 0.f, 0.f, 0.f);
            if (gr < NN) a4 = *(const float4*)&H[(size_t)gr * F0 + k0 + akq * 4];
            unsigned short* dst = &As[r][akq * 4];
            dst[0] = f2bf(a4.x); dst[1] = f2bf(a4.y); dst[2] = f2bf(a4.z); dst[3] = f2bf(a4.w);
        }
#pragma unroll
        for (int p = 0; p < 4; ++p) {
            int n = p * 32 + brow;
            uint4 b8 = *(const uint4*)&W1t[(bn + n) * F0 + k0 + bkq * 8];
            *(uint4*)&Bs[n][bkq * 8] = b8;
        }
        __syncthreads();
#pragma unroll
        for (int kk = 0; kk < 64; kk += 32) {
            s16x8 af[4], bfr[4];
#pragma unroll
            for (int mi = 0; mi < 4; ++mi)
                af[mi] = *(const s16x8*)&As[m_off + mi * 16 + l15][kk + quad * 8];
#pragma unroll
            for (int ni = 0; ni < 4; ++ni)
                bfr[ni] = *(const s16x8*)&Bs[n_off + ni * 16 + l15][kk + quad * 8];
#pragma unroll
            for (int mi = 0; mi < 4; ++mi)
#pragma unroll
                for (int ni = 0; ni < 4; ++ni)
                    acc[mi][ni] = __builtin_amdgcn_mfma_f32_16x16x32_bf16(af[mi], bfr[ni], acc[mi][ni], 0, 0, 0);
        }
    }
#pragma unroll
    for (int mi = 0; mi < 4; ++mi) {
        int r0 = bm + m_off + mi * 16 + quad * 4;
#pragma unroll
        for (int reg = 0; reg < 4; ++reg) {
            int gr = r0 + reg;
            if (gr < NN) {
                unsigned char* orow = &XW[(size_t)gr * F1 + bn + n_off];
#pragma unroll
                for (int ni = 0; ni < 4; ++ni) {
                    int pk = __builtin_amdgcn_cvt_pk_fp8_f32(acc[mi][ni][reg], 0.f, 0, false);
                    orow[ni * 16 + l15] = (unsigned char)(pk & 0xff);
                }
            }
        }
    }
}

// ---------------- SPMM1 + bias + relu + fused GEMM2 (fp8 gather, MLP=8) ----------------
__global__ __launch_bounds__(256) void k_spmm1(const unsigned char* __restrict__ XW, const int* __restrict__ rowptr,
                                               const int* __restrict__ colS, const float* __restrict__ wS,
                                               const float* __restrict__ b1, const float* __restrict__ W2,
                                               unsigned short* __restrict__ Z, float* __restrict__ Dv) {
    __shared__ float W2T[G * F1];
    const int tid = threadIdx.x;
    for (int idx = tid; idx < F1 * G; idx += 256) {
        int k = idx >> 4, j = idx & 15;
        W2T[j * F1 + k] = W2[idx];
    }
    __syncthreads();
    const int lane = tid & 63;
    const int n = blockIdx.x * 4 + (tid >> 6);
    const int s = __builtin_amdgcn_readfirstlane(rowptr[n]);
    const int e = __builtin_amdgcn_readfirstlane(rowptr[n + 1]);
    const unsigned* XWu = (const unsigned*)XW;

    float4 acc = make_float4(0.f, 0.f, 0.f, 0.f);
    float wsum = 0.f;
    int i = s;
    int pre = (s + 3) & ~3; if (pre > e) pre = e;
    for (; i < pre; ++i) {
        int c = colS[i]; float w = wS[i];
        unsigned g = XWu[(size_t)c * 64 + lane];
        f32x2 lo = __builtin_amdgcn_cvt_pk_f32_fp8(g, false);
        f32x2 hi = __builtin_amdgcn_cvt_pk_f32_fp8(g, true);
        acc.x = fmaf(w, lo.x, acc.x); acc.y = fmaf(w, lo.y, acc.y);
        acc.z = fmaf(w, hi.x, acc.z); acc.w = fmaf(w, hi.y, acc.w);
        wsum += w;
    }
    for (; i + 8 <= e; i += 8) {
        int4   c4a = *(const int4*)(colS + i);
        int4   c4b = *(const int4*)(colS + i + 4);
        float4 w4a = *(const float4*)(wS + i);
        float4 w4b = *(const float4*)(wS + i + 4);
        unsigned g0 = XWu[(size_t)c4a.x * 64 + lane];
        unsigned g1 = XWu[(size_t)c4a.y * 64 + lane];
        unsigned g2 = XWu[(size_t)c4a.z * 64 + lane];
        unsigned g3 = XWu[(size_t)c4a.w * 64 + lane];
        unsigned g4 = XWu[(size_t)c4b.x * 64 + lane];
        unsigned g5 = XWu[(size_t)c4b.y * 64 + lane];
        unsigned g6 = XWu[(size_t)c4b.z * 64 + lane];
        unsigned g7 = XWu[(size_t)c4b.w * 64 + lane];
        f32x2 v;
        v = __builtin_amdgcn_cvt_pk_f32_fp8(g0, false); acc.x = fmaf(w4a.x, v.x, acc.x); acc.y = fmaf(w4a.x, v.y, acc.y);
        v = __builtin_amdgcn_cvt_pk_f32_fp8(g0, true);  acc.z = fmaf(w4a.x, v.x, acc.z); acc.w = fmaf(w4a.x, v.y, acc.w);
        v = __builtin_amdgcn_cvt_pk_f32_fp8(g1, false); acc.x = fmaf(w4a.y, v.x, acc.x); acc.y = fmaf(w4a.y, v.y, acc.y);
        v = __builtin_amdgcn_cvt_pk_f32_fp8(g1, true);  acc.z = fmaf(w4a.y, v.x, acc.z); acc.w = fmaf(w4a.y, v.y, acc.w);
        v = __builtin_amdgcn_cvt_pk_f32_fp8(g2, false); acc.x = fmaf(w4a.z, v.x, acc.x); acc.y = fmaf(w4a.z, v.y, acc.y);
        v = __builtin_amdgcn_cvt_pk_f32_fp8(g2, true);  acc.z = fmaf(w4a.z, v.x, acc.z); acc.w = fmaf(w4a.z, v.y, acc.w);
        v = __builtin_amdgcn_cvt_pk_f32_fp8(g3, false); acc.x = fmaf(w4a.w, v.x, acc.x); acc.y = fmaf(w4a.w, v.y, acc.y);
        v = __builtin_amdgcn_cvt_pk_f32_fp8(g3, true);  acc.z = fmaf(w4a.w, v.x, acc.z); acc.w = fmaf(w4a.w, v.y, acc.w);
        v = __builtin_amdgcn_cvt_pk_f32_fp8(g4, false); acc.x = fmaf(w4b.x, v.x, acc.x); acc.y = fmaf(w4b.x, v.y, acc.y);
        v = __builtin_amdgcn_cvt_pk_f32_fp8(g4, true);  acc.z = fmaf(w4b.x, v.x, acc.z); acc.w = fmaf(w4b.x, v.y, acc.w);
        v = __builtin_amdgcn_cvt_pk_f32_fp8(g5, false); acc.x = fmaf(w4b.y, v.x, acc.x); acc.y = fmaf(w4b.y, v.y, acc.y);
        v = __builtin_amdgcn_cvt_pk_f32_fp8(g5, true);  acc.z = fmaf(w4b.y, v.x, acc.z); acc.w = fmaf(w4b.y, v.y, acc.w);
        v = __builtin_amdgcn_cvt_pk_f32_fp8(g6, false); acc.x = fmaf(w4b.z, v.x, acc.x); acc.y = fmaf(w4b.z, v.y, acc.y);
        v = __builtin_amdgcn_cvt_pk_f32_fp8(g6, true);  acc.z = fmaf(w4b.z, v.x, acc.z); acc.w = fmaf(w4b.z, v.y, acc.w);
        v = __builtin_amdgcn_cvt_pk_f32_fp8(g7, false); acc.x = fmaf(w4b.w, v.x, acc.x); acc.y = fmaf(w4b.w, v.y, acc.y);
        v = __builtin_amdgcn_cvt_pk_f32_fp8(g7, true);  acc.z = fmaf(w4b.w, v.x, acc.z); acc.w = fmaf(w4b.w, v.y, acc.w);
        wsum += w4a.x + w4a.y + w4a.z + w4a.w + w4b.x + w4b.y + w4b.z + w4b.w;
    }
    for (; i < e; ++i) {
        int c = colS[i]; float w = wS[i];
        unsigned g = XWu[(size_t)c * 64 + lane];
        f32x2 lo = __builtin_amdgcn_cvt_pk_f32_fp8(g, false);
        f32x2 hi = __builtin_amdgcn_cvt_pk_f32_fp8(g, true);
        acc.x = fmaf(w, lo.x, acc.x); acc.y = fmaf(w, lo.y, acc.y);
        acc.z = fmaf(w, hi.x, acc.z); acc.w = fmaf(w, hi.y, acc.w);
        wsum += w;
    }
    if (lane == 0) Dv[n] = wsum;

    float4 bb = *(const float4*)&b1[lane * 4];
    float4 h;
    h.x = fmaxf(acc.x + bb.x, 0.f);
    h.y = fmaxf(acc.y + bb.y, 0.f);
    h.z = fmaxf(acc.z + bb.z, 0.f);
    h.w = fmaxf(acc.w + bb.w, 0.f);

    float p[G];
#pragma unroll
    for (int j = 0; j < G; ++j) {
        float4 w4 = *(const float4*)&W2T[j * F1 + lane * 4];
        p[j] = h.x * w4.x + h.y * w4.y + h.z * w4.z + h.w * w4.w;
    }
#pragma unroll
    for (int off = 1; off < 64; off <<= 1) {
#pragma unroll
        for (int j = 0; j < G; ++j) p[j] += __shfl_xor(p[j], off, 64);
    }
    if (lane == 0) {
        unsigned zp[8];
#pragma unroll
        for (int j = 0; j < 8; ++j)
            zp[j] = (unsigned)f2bf(p[2 * j]) | ((unsigned)f2bf(p[2 * j + 1]) << 16);
        uint4* zo = (uint4*)&Z[n * G];
        zo[0] = make_uint4(zp[0], zp[1], zp[2], zp[3]);
        zo[1] = make_uint4(zp[4], zp[5], zp[6], zp[7]);
    }
}

// ---------------- SPMM2 + head + softmax + Gamma: 8 edges per gather instr ----------------
// lane = g*8+d: g=edge slot, d=dword index into Z row (8 dwords = 16 bf16).
__global__ __launch_bounds__(256) void k_head(const unsigned short* __restrict__ Zb, const int* __restrict__ rowptr,
                                              const int* __restrict__ colS, const float* __restrict__ wS,
                                              const float* __restrict__ b2, const float* __restrict__ Wl,
                                              const float* __restrict__ bl, const float* __restrict__ Dv,
                                              unsigned short* __restrict__ Yb, float* __restrict__ GammaP) {
    __shared__ float WlS[G * G];
    __shared__ float gsh[G];
    const int tid = threadIdx.x;
    if (tid < G * G) WlS[tid] = Wl[tid];
    if (tid < G) gsh[tid] = 0.f;
    __syncthreads();
    const int lane = tid & 63;
    const int g = lane >> 3;      // edge slot 0..7
    const int d = lane & 7;       // dword in row
    const int n = blockIdx.x * 4 + (tid >> 6);
    const int s = __builtin_amdgcn_readfirstlane(rowptr[n]);
    const int e = __builtin_amdgcn_readfirstlane(rowptr[n + 1]);
    const unsigned* Zu = (const unsigned*)Zb;

    float a0 = 0.f, a1 = 0.f;
    for (int base = s; base < e; base += 16) {
        int i0 = base + g;
        int i1 = base + 8 + g;
        int  c0 = (i0 < e) ? colS[i0] : 0;
        float w0 = (i0 < e) ? wS[i0] : 0.f;
        int  c1 = (i1 < e) ? colS[i1] : 0;
        float w1 = (i1 < e) ? wS[i1] : 0.f;
        unsigned z0 = Zu[(size_t)c0 * 8 + d];
        unsigned z1 = Zu[(size_t)c1 * 8 + d];
        a0 = fmaf(w0, bf2f((unsigned short)(z0 & 0xffff)), a0);
        a1 = fmaf(w0, bf2f((unsigned short)(z0 >> 16)), a1);
        a0 = fmaf(w1, bf2f((unsigned short)(z1 & 0xffff)), a0);
        a1 = fmaf(w1, bf2f((unsigned short)(z1 >> 16)), a1);
    }
    a0 += __shfl_xor(a0, 8, 64);  a1 += __shfl_xor(a1, 8, 64);
    a0 += __shfl_xor(a0, 16, 64); a1 += __shfl_xor(a1, 16, 64);
    a0 += __shfl_xor(a0, 32, 64); a1 += __shfl_xor(a1, 32, 64);

    const int j = lane & 15;
    float e0 = __shfl(a0, j >> 1, 64);
    float e1 = __shfl(a1, j >> 1, 64);
    float accj = (j & 1) ? e1 : e0;

    float h2 = fmaxf(accj + b2[j], 0.f);
    float s3 = 0.f;
#pragma unroll
    for (int k = 0; k < G; ++k) s3 = fmaf(__shfl(h2, k, 64), WlS[k * G + j], s3);
    float h3 = fmaxf(s3 + bl[j], 0.f);
    float m = h3;
    m = fmaxf(m, __shfl_xor(m, 1, 64));
    m = fmaxf(m, __shfl_xor(m, 2, 64));
    m = fmaxf(m, __shfl_xor(m, 4, 64));
    m = fmaxf(m, __shfl_xor(m, 8, 64));
    float ex = __expf(h3 - m);
    float se = ex;
    se += __shfl_xor(se, 1, 64);
    se += __shfl_xor(se, 2, 64);
    se += __shfl_xor(se, 4, 64);
    se += __shfl_xor(se, 8, 64);
    float y = ex / se;
    if (lane < G) {
        Yb[n * G + j] = f2bf(y);
        atomicAdd(&gsh[j], y * Dv[n]);
    }
    __syncthreads();
    if (tid < G) atomicAdd(&GammaP[(blockIdx.x & 63) * G + tid], gsh[tid]);
}

// ---------------- Gamma finalize ----------------
__global__ void k_gfin(const float* __restrict__ GammaP, float* __restrict__ invG) {
    int j = threadIdx.x;
    if (j < G) {
        float s = 0.f;
        for (int b = 0; b < 64; ++b) s += GammaP[b * G + j];
        invG[j] = 1.0f / s;
    }
}

// ---------------- edge loss (bf16 Y) ----------------
static __device__ __forceinline__ float dotrow(uint4 A, uint4 B, const f32x2* igp, int k0) {
    float t = 0.f;
    unsigned ua[4] = {A.x, A.y, A.z, A.w};
    unsigned ub[4] = {B.x, B.y, B.z, B.w};
#pragma unroll
    for (int k = 0; k < 4; ++k) {
        float arx = bf2f((unsigned short)(ua[k] & 0xffff));
        float ary = bf2f((unsigned short)(ua[k] >> 16));
        float acx = bf2f((unsigned short)(ub[k] & 0xffff));
        float acy = bf2f((unsigned short)(ub[k] >> 16));
        t += arx * acx * igp[k0 + k].x + ary * acy * igp[k0 + k].y;
    }
    return t;
}

__global__ __launch_bounds__(256) void k_loss(const int* __restrict__ row, const int* __restrict__ col,
                                              const float* __restrict__ ev, const unsigned short* __restrict__ Yb,
                                              const float* __restrict__ invG, float* __restrict__ lossAcc) {
    __shared__ float igs[G];
    __shared__ float pw[4];
    const int tid = threadIdx.x;
    if (tid < G) igs[tid] = invG[tid];
    __syncthreads();
    f32x2 igp[8];
#pragma unroll
    for (int k = 0; k < 8; ++k) { igp[k].x = igs[2 * k]; igp[k].y = igs[2 * k + 1]; }
    const int stride = gridDim.x * 256;
    float p0 = 0.f, p1 = 0.f;
    const uint4* Y4 = (const uint4*)Yb;   // row = 2 uint4
    for (int e0 = blockIdx.x * 256 + tid; e0 < NE; e0 += 2 * stride) {
        int r = row[e0], c = col[e0];
        float w = ev[e0];
        uint4 r0 = Y4[(size_t)r * 2], r1 = Y4[(size_t)r * 2 + 1];
        uint4 c0 = Y4[(size_t)c * 2], c1 = Y4[(size_t)c * 2 + 1];
        int e1 = e0 + stride;
        int rr = 0, cc = 0; float w2 = 0.f;
        if (e1 < NE) { rr = row[e1]; cc = col[e1]; w2 = ev[e1]; }
        uint4 r2 = Y4[(size_t)rr * 2], r3 = Y4[(size_t)rr * 2 + 1];
        uint4 c2 = Y4[(size_t)cc * 2], c3 = Y4[(size_t)cc * 2 + 1];
        float t0 = dotrow(r0, c0, igp, 0) + dotrow(r1, c1, igp, 4);
        float t1 = dotrow(r2, c2, igp, 0) + dotrow(r3, c3, igp, 4);
        p0 = fmaf(w, t0, p0);
        p1 = fmaf(w2, t1, p1);
    }
    float part = p0 + p1;
#pragma unroll
    for (int off = 1; off < 64; off <<= 1) part += __shfl_xor(part, off, 64);
    if ((tid & 63) == 0) pw[tid >> 6] = part;
    __syncthreads();
    if (tid == 0) atomicAdd(lossAcc, pw[0] + pw[1] + pw[2] + pw[3]);
}

__global__ void k_final(const float* __restrict__ lossAcc, float* __restrict__ out) {
    out[0] = 16.0f - lossAcc[0];
}

// ---------------- launcher ----------------
static inline size_t alignup(size_t x) { return (x + 255) & ~(size_t)255; }

extern "C" void kernel_launch(void* const* d_in, const int* in_sizes, int n_in,
                              void* d_out, int out_size, void* d_ws, size_t ws_size,
                              hipStream_t stream) {
    const float* H  = (const float*)d_in[0];
    const int*   ei = (const int*)d_in[1];
    const float* ev = (const float*)d_in[2];
    const float* W1 = (const float*)d_in[3];
    const float* b1 = (const float*)d_in[4];
    const float* W2 = (const float*)d_in[5];
    const float* b2 = (const float*)d_in[6];
    const float* Wl = (const float*)d_in[7];
    const float* bl = (const float*)d_in[8];
    const int* row = ei;
    const int* col = ei + NE;

    char* base = (char*)d_ws;
    size_t off = 0;
    unsigned char*  XW  = (unsigned char*)(base + off);  off = alignup(off + (size_t)NN * F1);
    unsigned short* W1t = (unsigned short*)(base + off); off = alignup(off + (size_t)F0 * F1 * 2);
    unsigned short* Z   = (unsigned short*)(base + off); off = alignup(off + (size_t)NN * G * 2);
    unsigned short* Yb  = (unsigned short*)(base + off); off = alignup(off + (size_t)NN * G * 2);
    float* Dv     = (float*)(base + off); off = alignup(off + (size_t)NN * 4);
    float* GammaP = (float*)(base + off); off = alignup(off + (size_t)64 * G * 4);
    float* invG   = (float*)(base + off); off = alignup(off + (size_t)G * 4);
    float* lossA  = (float*)(base + off); off = alignup(off + 4);
    int*   counts = (int*)(base + off);   off = alignup(off + (size_t)NN * 4);
    int*   rowptr = (int*)(base + off);   off = alignup(off + (size_t)(NN + 1) * 4);
    int*   cursor = (int*)(base + off);   off = alignup(off + (size_t)NN * 4);
    int*   bsum   = (int*)(base + off);   off = alignup(off + (size_t)NB * 4);
    int*   bofs   = (int*)(base + off);   off = alignup(off + (size_t)NB * 4);
    int*   colS   = (int*)(base + off);   off = alignup(off + (size_t)NE * 4);
    float* wS     = (float*)(base + off); off = alignup(off + (size_t)NE * 4);

    hipMemsetAsync(counts, 0, (size_t)NN * 4, stream);
    hipMemsetAsync(GammaP, 0, (size_t)64 * G * 4, stream);
    hipMemsetAsync(lossA, 0, 4, stream);

    k_hist<<<dim3((NE / 4 + 255) / 256), dim3(256), 0, stream>>>(row, counts);
    k_scan1<<<dim3(NB), dim3(1024), 0, stream>>>(counts, bsum);
    k_scan2<<<dim3(1), dim3(64), 0, stream>>>(bsum, bofs, rowptr);
    k_scan3<<<dim3(NB), dim3(1024), 0, stream>>>(counts, bofs, rowptr, cursor);
    k_scatter<<<dim3((NE / 4 + 255) / 256), dim3(256), 0, stream>>>(row, col, ev, cursor, colS, wS);
    k_castW1<<<dim3((F0 * F1 + 255) / 256), dim3(256), 0, stream>>>(W1, W1t);
    k_gemm1<<<dim3((NN + 127) / 128, F1 / 128), dim3(256), 0, stream>>>(H, W1t, XW);
    k_spmm1<<<dim3(NN / 4), dim3(256), 0, stream>>>(XW, rowptr, colS, wS, b1, W2, Z, Dv);
    k_head<<<dim3(NN / 4), dim3(256), 0, stream>>>(Z, rowptr, colS, wS, b2, Wl, bl, Dv, Yb, GammaP);
    k_gfin<<<dim3(1), dim3(64), 0, stream>>>(GammaP, invG);
    k_loss<<<dim3(1024), dim3(256), 0, stream>>>(row, col, ev, Yb, invG, lossA);
    k_final<<<dim3(1), dim3(1), 0, stream>>>(lossA, (float*)d_out);
}

// Round 6
// 557.036 us; speedup vs baseline: 1.7594x; 1.0745x over previous
//
#include <hip/hip_runtime.h>

// GCN forward + NCut loss on MI355X.
// R6 (=R5 with compile fix): source-tiled bucketed CSR (4 tiles of 12500 src nodes;
//     key = 4*row + tile(col)) -> spmm1 gathers are L2-resident per tile-phase;
//     uniform scalar edge loads with precomputed byte offsets; W2T LDS conflict fix;
//     nontemporal edge streams (ext_vector types for the builtin).
// loss = 16 - sum_e w_e * sum_j Y[row,j]*Y[col,j]/Gamma[j]

constexpr int NN = 50000;
constexpr int NE = 1600000;
constexpr int F0 = 512;
constexpr int F1 = 256;
constexpr int G  = 16;
constexpr int NT = 4;                      // source tiles
constexpr int NK = NN * NT;                // bucketed keys
constexpr int NB2 = (NK + 1023) / 1024;    // 196 scan blocks
constexpr unsigned long long TMAG = 175921861ULL;  // ceil(2^41/12500)

typedef short  s16x8 __attribute__((ext_vector_type(8)));
typedef float  f32x4 __attribute__((ext_vector_type(4)));
typedef float  f32x2 __attribute__((ext_vector_type(2)));
typedef int    i32x4 __attribute__((ext_vector_type(4)));
typedef float  fv4   __attribute__((ext_vector_type(4)));

static __device__ __forceinline__ unsigned short f2bf(float f) {
    union { float f; unsigned u; } v; v.f = f;
    unsigned r = (v.u + 0x7FFFu + ((v.u >> 16) & 1u)) >> 16;   // RNE
    return (unsigned short)r;
}
static __device__ __forceinline__ float bf2f(unsigned short u) {
    union { unsigned u; float f; } v; v.u = (unsigned)u << 16;
    return v.f;
}
static __device__ __forceinline__ int srctile(int c) {
    return (int)(((unsigned long long)(unsigned)c * TMAG) >> 41);   // c / 12500
}

// ---------------- CSR build (bucketed by (row, srctile(col))) ----------------
__global__ __launch_bounds__(256) void k_hist(const int* __restrict__ row, const int* __restrict__ col,
                                              int* __restrict__ counts) {
    int idx = blockIdx.x * 256 + threadIdx.x;
    if (idx < NE / 4) {
        i32x4 r = __builtin_nontemporal_load(&((const i32x4*)row)[idx]);
        i32x4 c = __builtin_nontemporal_load(&((const i32x4*)col)[idx]);
        atomicAdd(&counts[(r.x << 2) | srctile(c.x)], 1);
        atomicAdd(&counts[(r.y << 2) | srctile(c.y)], 1);
        atomicAdd(&counts[(r.z << 2) | srctile(c.z)], 1);
        atomicAdd(&counts[(r.w << 2) | srctile(c.w)], 1);
    }
}

__global__ __launch_bounds__(1024) void k_scan1(const int* __restrict__ counts, int* __restrict__ bsum) {
    __shared__ int sh[1024];
    const int tid = threadIdx.x;
    int i = blockIdx.x * 1024 + tid;
    sh[tid] = (i < NK) ? counts[i] : 0;
    __syncthreads();
    for (int off = 512; off > 0; off >>= 1) {
        if (tid < off) sh[tid] += sh[tid + off];
        __syncthreads();
    }
    if (tid == 0) bsum[blockIdx.x] = sh[0];
}

__global__ __launch_bounds__(256) void k_scan2(const int* __restrict__ bsum, int* __restrict__ bofs,
                                               int* __restrict__ rowptr) {
    __shared__ int sh[256];
    const int tid = threadIdx.x;
    int orig = (tid < NB2) ? bsum[tid] : 0;
    sh[tid] = orig;
    __syncthreads();
    for (int off = 1; off < 256; off <<= 1) {
        int t = (tid >= off) ? sh[tid - off] : 0;
        __syncthreads();
        sh[tid] += t;
        __syncthreads();
    }
    if (tid < NB2) bofs[tid] = sh[tid] - orig;   // exclusive
    if (tid == 255) rowptr[NK] = sh[255];
}

__global__ __launch_bounds__(1024) void k_scan3(const int* __restrict__ counts, const int* __restrict__ bofs,
                                                int* __restrict__ rowptr, int* __restrict__ cursor) {
    __shared__ int sh[1024];
    const int tid = threadIdx.x;
    int i = blockIdx.x * 1024 + tid;
    int orig = (i < NK) ? counts[i] : 0;
    sh[tid] = orig;
    __syncthreads();
    for (int off = 1; off < 1024; off <<= 1) {
        int t = (tid >= off) ? sh[tid - off] : 0;
        __syncthreads();
        sh[tid] += t;
        __syncthreads();
    }
    int ex = sh[tid] - orig + bofs[blockIdx.x];
    if (i < NK) { rowptr[i] = ex; cursor[i] = ex; }
}

__global__ __launch_bounds__(256) void k_scatter(const int* __restrict__ row, const int* __restrict__ col,
                                                 const float* __restrict__ ev, int* __restrict__ cursor,
                                                 int* __restrict__ colB, float* __restrict__ wS) {
    int idx = blockIdx.x * 256 + threadIdx.x;
    if (idx < NE / 4) {
        i32x4 r = __builtin_nontemporal_load(&((const i32x4*)row)[idx]);
        i32x4 c = __builtin_nontemporal_load(&((const i32x4*)col)[idx]);
        fv4   w = __builtin_nontemporal_load(&((const fv4*)ev)[idx]);
        int p;
        p = atomicAdd(&cursor[(r.x << 2) | srctile(c.x)], 1); colB[p] = c.x << 8; wS[p] = w.x;
        p = atomicAdd(&cursor[(r.y << 2) | srctile(c.y)], 1); colB[p] = c.y << 8; wS[p] = w.y;
        p = atomicAdd(&cursor[(r.z << 2) | srctile(c.z)], 1); colB[p] = c.z << 8; wS[p] = w.z;
        p = atomicAdd(&cursor[(r.w << 2) | srctile(c.w)], 1); colB[p] = c.w << 8; wS[p] = w.w;
    }
}

// ---------------- W1 pre-cast+transpose ----------------
__global__ __launch_bounds__(256) void k_castW1(const float* __restrict__ W1, unsigned short* __restrict__ W1t) {
    int idx = blockIdx.x * 256 + threadIdx.x;
    if (idx < F0 * F1) {
        int k = idx >> 8, n = idx & 255;
        W1t[n * F0 + k] = f2bf(W1[idx]);
    }
}

// ---------------- GEMM1 (bf16 MFMA): XW = fp8(H @ W1) ----------------
__global__ __launch_bounds__(256) void k_gemm1(const float* __restrict__ H, const unsigned short* __restrict__ W1t,
                                               unsigned char* __restrict__ XW) {
    __shared__ unsigned short As[128][72];
    __shared__ unsigned short Bs[128][72];
    const int tid  = threadIdx.x;
    const int lane = tid & 63;
    const int wave = tid >> 6;
    const int bm = blockIdx.x * 128;
    const int bn = blockIdx.y * 128;
    const int m_off = (wave & 1) * 64;
    const int n_off = (wave >> 1) * 64;
    const int l15  = lane & 15;
    const int quad = lane >> 4;

    f32x4 acc[4][4];
#pragma unroll
    for (int i = 0; i < 4; ++i)
#pragma unroll
        for (int j = 0; j < 4; ++j) acc[i][j] = (f32x4)0.f;

    const int arow = tid >> 4;
    const int akq  = tid & 15;
    const int brow = tid >> 3;
    const int bkq  = tid & 7;

    for (int k0 = 0; k0 < F0; k0 += 64) {
        __syncthreads();
#pragma unroll
        for (int p = 0; p < 8; ++p) {
            int r = p * 16 + arow;
            int gr = bm + r;
            float4 a4 = make_float4(0.f, 0.f, 0.f, 0.f);
            if (gr < NN) a4 = *(const float4*)&H[(size_t)gr * F0 + k0 + akq * 4];
            unsigned short* dst = &As[r][akq * 4];
            dst[0] = f2bf(a4.x); dst[1] = f2bf(a4.y); dst[2] = f2bf(a4.z); dst[3] = f2bf(a4.w);
        }
#pragma unroll
        for (int p = 0; p < 4; ++p) {
            int n = p * 32 + brow;
            uint4 b8 = *(const uint4*)&W1t[(bn + n) * F0 + k0 + bkq * 8];
            *(uint4*)&Bs[n][bkq * 8] = b8;
        }
        __syncthreads();
#pragma unroll
        for (int kk = 0; kk < 64; kk += 32) {
            s16x8 af[4], bfr[4];
#pragma unroll
            for (int mi = 0; mi < 4; ++mi)
                af[mi] = *(const s16x8*)&As[m_off + mi * 16 + l15][kk + quad * 8];
#pragma unroll
            for (int ni = 0; ni < 4; ++ni)
                bfr[ni] = *(const s16x8*)&Bs[n_off + ni * 16 + l15][kk + quad * 8];
#pragma unroll
            for (int mi = 0; mi < 4; ++mi)
#pragma unroll
                for (int ni = 0; ni < 4; ++ni)
                    acc[mi][ni] = __builtin_amdgcn_mfma_f32_16x16x32_bf16(af[mi], bfr[ni], acc[mi][ni], 0, 0, 0);
        }
    }
#pragma unroll
    for (int mi = 0; mi < 4; ++mi) {
        int r0 = bm + m_off + mi * 16 + quad * 4;
#pragma unroll
        for (int reg = 0; reg < 4; ++reg) {
            int gr = r0 + reg;
            if (gr < NN) {
                unsigned char* orow = &XW[(size_t)gr * F1 + bn + n_off];
#pragma unroll
                for (int ni = 0; ni < 4; ++ni) {
                    int pk = __builtin_amdgcn_cvt_pk_fp8_f32(acc[mi][ni][reg], 0.f, 0, false);
                    orow[ni * 16 + l15] = (unsigned char)(pk & 0xff);
                }
            }
        }
    }
}

// ---------------- SPMM1 + bias + relu + fused GEMM2 (tiled fp8 gather) ----------------
__global__ __launch_bounds__(256) void k_spmm1(const unsigned char* __restrict__ XW, const int* __restrict__ rowptr,
                                               const int* __restrict__ colB, const float* __restrict__ wS,
                                               const float* __restrict__ b1, const float* __restrict__ W2,
                                               unsigned short* __restrict__ Z, float* __restrict__ Dv) {
    __shared__ float W2T[G * F1];
    const int tid = threadIdx.x;
#pragma unroll
    for (int it = 0; it < 16; ++it)
        W2T[it * 256 + tid] = W2[tid * 16 + it];   // conflict-free writes
    __syncthreads();
    const int lane = tid & 63;
    const int lane4 = lane * 4;
    const int n = blockIdx.x * 4 + (tid >> 6);
    int4 sv = *(const int4*)&rowptr[4 * n];
    int segs[5];
    segs[0] = __builtin_amdgcn_readfirstlane(sv.x);
    segs[1] = __builtin_amdgcn_readfirstlane(sv.y);
    segs[2] = __builtin_amdgcn_readfirstlane(sv.z);
    segs[3] = __builtin_amdgcn_readfirstlane(sv.w);
    segs[4] = __builtin_amdgcn_readfirstlane(rowptr[4 * n + 4]);

    float4 acc = make_float4(0.f, 0.f, 0.f, 0.f);
    float wsum = 0.f;
#pragma unroll
    for (int t = 0; t < NT; ++t) {
        const int ss = segs[t], se = segs[t + 1];
        int i = ss;
        for (; i + 8 <= se; i += 8) {          // full chunks: uniform scalar edge loads
            int of[8]; float w[8];
#pragma unroll
            for (int k = 0; k < 8; ++k) { of[k] = colB[i + k]; w[k] = wS[i + k]; }
            unsigned gg[8];
#pragma unroll
            for (int k = 0; k < 8; ++k) gg[k] = *(const unsigned*)(XW + of[k] + lane4);
#pragma unroll
            for (int k = 0; k < 8; ++k) {
                f32x2 lo = __builtin_amdgcn_cvt_pk_f32_fp8(gg[k], false);
                f32x2 hi = __builtin_amdgcn_cvt_pk_f32_fp8(gg[k], true);
                acc.x = fmaf(w[k], lo.x, acc.x); acc.y = fmaf(w[k], lo.y, acc.y);
                acc.z = fmaf(w[k], hi.x, acc.z); acc.w = fmaf(w[k], hi.y, acc.w);
                wsum += w[k];
            }
        }
        for (; i < se; i += 4) {               // guarded tail
            int of[4]; float w[4];
#pragma unroll
            for (int k = 0; k < 4; ++k) {
                int idx = i + k;
                bool ok = idx < se;
                of[k] = colB[ok ? idx : ss];
                w[k]  = ok ? wS[idx] : 0.f;
            }
            unsigned gg[4];
#pragma unroll
            for (int k = 0; k < 4; ++k) gg[k] = *(const unsigned*)(XW + of[k] + lane4);
#pragma unroll
            for (int k = 0; k < 4; ++k) {
                f32x2 lo = __builtin_amdgcn_cvt_pk_f32_fp8(gg[k], false);
                f32x2 hi = __builtin_amdgcn_cvt_pk_f32_fp8(gg[k], true);
                acc.x = fmaf(w[k], lo.x, acc.x); acc.y = fmaf(w[k], lo.y, acc.y);
                acc.z = fmaf(w[k], hi.x, acc.z); acc.w = fmaf(w[k], hi.y, acc.w);
                wsum += w[k];
            }
        }
    }
    if (lane == 0) Dv[n] = wsum;

    float4 bb = *(const float4*)&b1[lane * 4];
    float4 h;
    h.x = fmaxf(acc.x + bb.x, 0.f);
    h.y = fmaxf(acc.y + bb.y, 0.f);
    h.z = fmaxf(acc.z + bb.z, 0.f);
    h.w = fmaxf(acc.w + bb.w, 0.f);

    float p[G];
#pragma unroll
    for (int j = 0; j < G; ++j) {
        float4 w4 = *(const float4*)&W2T[j * F1 + lane * 4];
        p[j] = h.x * w4.x + h.y * w4.y + h.z * w4.z + h.w * w4.w;
    }
#pragma unroll
    for (int off = 1; off < 64; off <<= 1) {
#pragma unroll
        for (int j = 0; j < G; ++j) p[j] += __shfl_xor(p[j], off, 64);
    }
    if (lane == 0) {
        unsigned zp[8];
#pragma unroll
        for (int j = 0; j < 8; ++j)
            zp[j] = (unsigned)f2bf(p[2 * j]) | ((unsigned)f2bf(p[2 * j + 1]) << 16);
        uint4* zo = (uint4*)&Z[n * G];
        zo[0] = make_uint4(zp[0], zp[1], zp[2], zp[3]);
        zo[1] = make_uint4(zp[4], zp[5], zp[6], zp[7]);
    }
}

// ---------------- SPMM2 + head + softmax + Gamma: 8 edges per gather instr ----------------
__global__ __launch_bounds__(256) void k_head(const unsigned short* __restrict__ Zb, const int* __restrict__ rowptr,
                                              const int* __restrict__ colB, const float* __restrict__ wS,
                                              const float* __restrict__ b2, const float* __restrict__ Wl,
                                              const float* __restrict__ bl, const float* __restrict__ Dv,
                                              unsigned short* __restrict__ Yb, float* __restrict__ GammaP) {
    __shared__ float WlS[G * G];
    __shared__ float gsh[G];
    const int tid = threadIdx.x;
    if (tid < G * G) WlS[tid] = Wl[tid];
    if (tid < G) gsh[tid] = 0.f;
    __syncthreads();
    const int lane = tid & 63;
    const int g = lane >> 3;      // edge slot 0..7
    const int d = lane & 7;       // dword in Z row
    const int n = blockIdx.x * 4 + (tid >> 6);
    const int s = __builtin_amdgcn_readfirstlane(rowptr[4 * n]);
    const int e = __builtin_amdgcn_readfirstlane(rowptr[4 * n + 4]);
    const char* Zc = (const char*)Zb;

    float a0 = 0.f, a1 = 0.f;
    for (int base = s; base < e; base += 16) {
        int i0 = base + g;
        int i1 = base + 8 + g;
        int  cb0 = (i0 < e) ? colB[i0] : colB[s];
        float w0 = (i0 < e) ? wS[i0] : 0.f;
        int  cb1 = (i1 < e) ? colB[i1] : colB[s];
        float w1 = (i1 < e) ? wS[i1] : 0.f;
        unsigned z0 = *(const unsigned*)(Zc + (cb0 >> 3) + d * 4);
        unsigned z1 = *(const unsigned*)(Zc + (cb1 >> 3) + d * 4);
        a0 = fmaf(w0, bf2f((unsigned short)(z0 & 0xffff)), a0);
        a1 = fmaf(w0, bf2f((unsigned short)(z0 >> 16)), a1);
        a0 = fmaf(w1, bf2f((unsigned short)(z1 & 0xffff)), a0);
        a1 = fmaf(w1, bf2f((unsigned short)(z1 >> 16)), a1);
    }
    a0 += __shfl_xor(a0, 8, 64);  a1 += __shfl_xor(a1, 8, 64);
    a0 += __shfl_xor(a0, 16, 64); a1 += __shfl_xor(a1, 16, 64);
    a0 += __shfl_xor(a0, 32, 64); a1 += __shfl_xor(a1, 32, 64);

    const int j = lane & 15;
    float e0 = __shfl(a0, j >> 1, 64);
    float e1 = __shfl(a1, j >> 1, 64);
    float accj = (j & 1) ? e1 : e0;

    float h2 = fmaxf(accj + b2[j], 0.f);
    float s3 = 0.f;
#pragma unroll
    for (int k = 0; k < G; ++k) s3 = fmaf(__shfl(h2, k, 64), WlS[k * G + j], s3);
    float h3 = fmaxf(s3 + bl[j], 0.f);
    float m = h3;
    m = fmaxf(m, __shfl_xor(m, 1, 64));
    m = fmaxf(m, __shfl_xor(m, 2, 64));
    m = fmaxf(m, __shfl_xor(m, 4, 64));
    m = fmaxf(m, __shfl_xor(m, 8, 64));
    float ex = __expf(h3 - m);
    float se = ex;
    se += __shfl_xor(se, 1, 64);
    se += __shfl_xor(se, 2, 64);
    se += __shfl_xor(se, 4, 64);
    se += __shfl_xor(se, 8, 64);
    float y = ex / se;
    if (lane < G) {
        Yb[n * G + j] = f2bf(y);
        atomicAdd(&gsh[j], y * Dv[n]);
    }
    __syncthreads();
    if (tid < G) atomicAdd(&GammaP[(blockIdx.x & 63) * G + tid], gsh[tid]);
}

// ---------------- Gamma finalize ----------------
__global__ void k_gfin(const float* __restrict__ GammaP, float* __restrict__ invG) {
    int j = threadIdx.x;
    if (j < G) {
        float s = 0.f;
        for (int b = 0; b < 64; ++b) s += GammaP[b * G + j];
        invG[j] = 1.0f / s;
    }
}

// ---------------- edge loss (bf16 Y) ----------------
static __device__ __forceinline__ float dotrow(uint4 A, uint4 B, const f32x2* igp, int k0) {
    float t = 0.f;
    unsigned ua[4] = {A.x, A.y, A.z, A.w};
    unsigned ub[4] = {B.x, B.y, B.z, B.w};
#pragma unroll
    for (int k = 0; k < 4; ++k) {
        float arx = bf2f((unsigned short)(ua[k] & 0xffff));
        float ary = bf2f((unsigned short)(ua[k] >> 16));
        float acx = bf2f((unsigned short)(ub[k] & 0xffff));
        float acy = bf2f((unsigned short)(ub[k] >> 16));
        t += arx * acx * igp[k0 + k].x + ary * acy * igp[k0 + k].y;
    }
    return t;
}

__global__ __launch_bounds__(256) void k_loss(const int* __restrict__ row, const int* __restrict__ col,
                                              const float* __restrict__ ev, const unsigned short* __restrict__ Yb,
                                              const float* __restrict__ invG, float* __restrict__ lossAcc) {
    __shared__ float igs[G];
    __shared__ float pw[4];
    const int tid = threadIdx.x;
    if (tid < G) igs[tid] = invG[tid];
    __syncthreads();
    f32x2 igp[8];
#pragma unroll
    for (int k = 0; k < 8; ++k) { igp[k].x = igs[2 * k]; igp[k].y = igs[2 * k + 1]; }
    const int stride = gridDim.x * 256;
    float p0 = 0.f, p1 = 0.f;
    const uint4* Y4 = (const uint4*)Yb;
    for (int e0 = blockIdx.x * 256 + tid; e0 < NE; e0 += 2 * stride) {
        int r = __builtin_nontemporal_load(&row[e0]);
        int c = __builtin_nontemporal_load(&col[e0]);
        float w = __builtin_nontemporal_load(&ev[e0]);
        uint4 r0 = Y4[(size_t)r * 2], r1 = Y4[(size_t)r * 2 + 1];
        uint4 c0 = Y4[(size_t)c * 2], c1 = Y4[(size_t)c * 2 + 1];
        int e1 = e0 + stride;
        int rr = 0, cc = 0; float w2 = 0.f;
        if (e1 < NE) {
            rr = __builtin_nontemporal_load(&row[e1]);
            cc = __builtin_nontemporal_load(&col[e1]);
            w2 = __builtin_nontemporal_load(&ev[e1]);
        }
        uint4 r2 = Y4[(size_t)rr * 2], r3 = Y4[(size_t)rr * 2 + 1];
        uint4 c2 = Y4[(size_t)cc * 2], c3 = Y4[(size_t)cc * 2 + 1];
        float t0 = dotrow(r0, c0, igp, 0) + dotrow(r1, c1, igp, 4);
        float t1 = dotrow(r2, c2, igp, 0) + dotrow(r3, c3, igp, 4);
        p0 = fmaf(w, t0, p0);
        p1 = fmaf(w2, t1, p1);
    }
    float part = p0 + p1;
#pragma unroll
    for (int off = 1; off < 64; off <<= 1) part += __shfl_xor(part, off, 64);
    if ((tid & 63) == 0) pw[tid >> 6] = part;
    __syncthreads();
    if (tid == 0) atomicAdd(lossAcc, pw[0] + pw[1] + pw[2] + pw[3]);
}

__global__ void k_final(const float* __restrict__ lossAcc, float* __restrict__ out) {
    out[0] = 16.0f - lossAcc[0];
}

// ---------------- launcher ----------------
static inline size_t alignup(size_t x) { return (x + 255) & ~(size_t)255; }

extern "C" void kernel_launch(void* const* d_in, const int* in_sizes, int n_in,
                              void* d_out, int out_size, void* d_ws, size_t ws_size,
                              hipStream_t stream) {
    const float* H  = (const float*)d_in[0];
    const int*   ei = (const int*)d_in[1];
    const float* ev = (const float*)d_in[2];
    const float* W1 = (const float*)d_in[3];
    const float* b1 = (const float*)d_in[4];
    const float* W2 = (const float*)d_in[5];
    const float* b2 = (const float*)d_in[6];
    const float* Wl = (const float*)d_in[7];
    const float* bl = (const float*)d_in[8];
    const int* row = ei;
    const int* col = ei + NE;

    char* base = (char*)d_ws;
    size_t off = 0;
    unsigned char*  XW  = (unsigned char*)(base + off);  off = alignup(off + (size_t)NN * F1);
    unsigned short* W1t = (unsigned short*)(base + off); off = alignup(off + (size_t)F0 * F1 * 2);
    unsigned short* Z   = (unsigned short*)(base + off); off = alignup(off + (size_t)NN * G * 2);
    unsigned short* Yb  = (unsigned short*)(base + off); off = alignup(off + (size_t)NN * G * 2);
    float* Dv     = (float*)(base + off); off = alignup(off + (size_t)NN * 4);
    float* GammaP = (float*)(base + off); off = alignup(off + (size_t)64 * G * 4);
    float* invG   = (float*)(base + off); off = alignup(off + (size_t)G * 4);
    float* lossA  = (float*)(base + off); off = alignup(off + 4);
    int*   counts = (int*)(base + off);   off = alignup(off + (size_t)NK * 4);
    int*   rowptr = (int*)(base + off);   off = alignup(off + (size_t)(NK + 1) * 4);
    int*   cursor = (int*)(base + off);   off = alignup(off + (size_t)NK * 4);
    int*   bsum   = (int*)(base + off);   off = alignup(off + (size_t)NB2 * 4);
    int*   bofs   = (int*)(base + off);   off = alignup(off + (size_t)NB2 * 4);
    int*   colB   = (int*)(base + off);   off = alignup(off + (size_t)NE * 4);
    float* wS     = (float*)(base + off); off = alignup(off + (size_t)NE * 4);

    hipMemsetAsync(counts, 0, (size_t)NK * 4, stream);
    hipMemsetAsync(GammaP, 0, (size_t)64 * G * 4, stream);
    hipMemsetAsync(lossA, 0, 4, stream);

    k_hist<<<dim3((NE / 4 + 255) / 256), dim3(256), 0, stream>>>(row, col, counts);
    k_scan1<<<dim3(NB2), dim3(1024), 0, stream>>>(counts, bsum);
    k_scan2<<<dim3(1), dim3(256), 0, stream>>>(bsum, bofs, rowptr);
    k_scan3<<<dim3(NB2), dim3(1024), 0, stream>>>(counts, bofs, rowptr, cursor);
    k_scatter<<<dim3((NE / 4 + 255) / 256), dim3(256), 0, stream>>>(row, col, ev, cursor, colB, wS);
    k_castW1<<<dim3((F0 * F1 + 255) / 256), dim3(256), 0, stream>>>(W1, W1t);
    k_gemm1<<<dim3((NN + 127) / 128, F1 / 128), dim3(256), 0, stream>>>(H, W1t, XW);
    k_spmm1<<<dim3(NN / 4), dim3(256), 0, stream>>>(XW, rowptr, colB, wS, b1, W2, Z, Dv);
    k_head<<<dim3(NN / 4), dim3(256), 0, stream>>>(Z, rowptr, colB, wS, b2, Wl, bl, Dv, Yb, GammaP);
    k_gfin<<<dim3(1), dim3(64), 0, stream>>>(GammaP, invG);
    k_loss<<<dim3(1024), dim3(256), 0, stream>>>(row, col, ev, Yb, invG, lossA);
    k_final<<<dim3(1), dim3(1), 0, stream>>>(lossA, (float*)d_out);
}